// Round 1
// baseline (907.722 us; speedup 1.0000x reference)
//
#include <hip/hip_runtime.h>

typedef unsigned short u16;
typedef short bfrag __attribute__((ext_vector_type(8)));   // 8 bf16 = one MFMA A/B frag
typedef float ffrag __attribute__((ext_vector_type(4)));   // MFMA C/D frag

#define MFMA16(a,b,c) __builtin_amdgcn_mfma_f32_16x16x32_bf16((a),(b),(c),0,0,0)

// B=2, C=256, H=64, W=512 ; HW=32768 ; PIX=65536 ; NROW=B*H=128 ; max_w=int(512*0.26)=133

__device__ __forceinline__ u16 f2bf(float f){
  union { float f; unsigned int i; } cv; cv.f = f;
  unsigned int x = cv.i;
  return (u16)((x + 0x7fffu + ((x >> 16) & 1u)) >> 16);  // RNE
}
__device__ __forceinline__ float bf2f(u16 u){
  union { unsigned int i; float f; } cv;
  cv.i = ((unsigned int)u) << 16;
  return cv.f;
}
__device__ __forceinline__ bfrag ldb(const u16* p){
  bfrag v; __builtin_memcpy(&v, p, 16); return v;
}

// ---------- weights fp32 -> bf16 (Qw,Kw,Vw,Ww each 256x256, (o,c) row-major) ----------
__global__ __launch_bounds__(256) void k_wcvt(const float* __restrict__ qw, const float* __restrict__ kw,
                                              const float* __restrict__ vw, const float* __restrict__ ww,
                                              u16* __restrict__ out){
  int t = blockIdx.x*256 + threadIdx.x;           // 0..65535
  out[t]        = f2bf(qw[t]);
  out[t+65536]  = f2bf(kw[t]);
  out[t+131072] = f2bf(vw[t]);
  out[t+196608] = f2bf(ww[t]);
}

// ---------- x (B,C,H,W) fp32 -> xr (p, c) bf16, p = b*HW + h*W + w ----------
__global__ __launch_bounds__(256) void k_xpose(const float* __restrict__ x, u16* __restrict__ xr){
  __shared__ float T[64][65];
  int t = threadIdx.x;
  int p0 = blockIdx.x*64, c0 = blockIdx.y*64;
  int b = p0 >> 15, q0 = p0 & 32767;
  #pragma unroll
  for (int it=0; it<4; ++it){
    int cc = it*16 + (t>>4);
    int pi = (t&15)*4;
    ffrag v; __builtin_memcpy(&v, x + ((size_t)(b*256 + c0 + cc))*32768 + q0 + pi, 16);
    T[cc][pi+0]=v[0]; T[cc][pi+1]=v[1]; T[cc][pi+2]=v[2]; T[cc][pi+3]=v[3];
  }
  __syncthreads();
  int pi = t>>2, cj0 = (t&3)*16;
  u16 tmp[16];
  #pragma unroll
  for (int j=0;j<16;++j) tmp[j] = f2bf(T[cj0+j][pi]);
  __builtin_memcpy(xr + (size_t)(p0+pi)*256 + c0 + cj0, tmp, 32);
}

// ---------- QKV conv: Y = X*Wt + b for 3 weights; V written transposed (n,c,w) ----------
__global__ __launch_bounds__(256) void k_qkv(const u16* __restrict__ xr, const u16* __restrict__ wb,
    const float* __restrict__ qb, const float* __restrict__ kb, const float* __restrict__ vb,
    u16* __restrict__ Qo, u16* __restrict__ Ko, u16* __restrict__ Vt){
  int t = threadIdx.x, wid = t>>6, l = t&63, lr = l&15, lg = l>>4;
  int p0 = blockIdx.x*64, o0 = blockIdx.y*64;
  int msub = (wid&1)*32, nsub = (wid>>1)*32;
  int pbase = p0 + msub;

  bfrag a[2][8];
  #pragma unroll
  for (int mt=0; mt<2; ++mt)
    #pragma unroll
    for (int ks=0; ks<8; ++ks)
      a[mt][ks] = ldb(xr + (size_t)(pbase + mt*16 + lr)*256 + ks*32 + lg*8);

  const ffrag fz = {0.f,0.f,0.f,0.f};
  #pragma unroll
  for (int wgt=0; wgt<3; ++wgt){
    const u16* wp = wb + wgt*65536;
    const float* bias = (wgt==0)? qb : (wgt==1)? kb : vb;
    ffrag acc[2][2];
    acc[0][0]=fz; acc[0][1]=fz; acc[1][0]=fz; acc[1][1]=fz;
    #pragma unroll
    for (int nt=0; nt<2; ++nt)
      #pragma unroll
      for (int ks=0; ks<8; ++ks){
        bfrag b = ldb(wp + (size_t)(o0 + nsub + nt*16 + lr)*256 + ks*32 + lg*8);
        acc[0][nt] = MFMA16(a[0][ks], b, acc[0][nt]);
        acc[1][nt] = MFMA16(a[1][ks], b, acc[1][nt]);
      }
    #pragma unroll
    for (int nt=0; nt<2; ++nt){
      int oo = o0 + nsub + nt*16 + lr;
      float bs = bias[oo];
      #pragma unroll
      for (int mt=0; mt<2; ++mt){
        int pr = pbase + mt*16 + lg*4;
        if (wgt == 2){
          int n = pr >> 9, w0 = pr & 511;
          u16 vv[4];
          #pragma unroll
          for (int r=0;r<4;++r) vv[r] = f2bf(acc[mt][nt][r] + bs);
          __builtin_memcpy(Vt + ((size_t)(n*256 + oo))*512 + w0, vv, 8);
        } else {
          u16* op = (wgt==0)? Qo : Ko;
          #pragma unroll
          for (int r=0;r<4;++r)
            op[(size_t)(pr + r)*256 + oo] = f2bf(acc[mt][nt][r] + bs);
        }
      }
    }
  }
}

// ---------- generic 1-weight conv (used for W conv): in (p,c) bf16 -> out (p,c) bf16 ----------
__global__ __launch_bounds__(256) void k_conv1(const u16* __restrict__ xin, const u16* __restrict__ wp,
    const float* __restrict__ bias, u16* __restrict__ out){
  int t = threadIdx.x, wid = t>>6, l = t&63, lr = l&15, lg = l>>4;
  int p0 = blockIdx.x*64, o0 = blockIdx.y*64;
  int msub = (wid&1)*32, nsub = (wid>>1)*32;
  int pbase = p0 + msub;
  bfrag a[2][8];
  #pragma unroll
  for (int mt=0; mt<2; ++mt)
    #pragma unroll
    for (int ks=0; ks<8; ++ks)
      a[mt][ks] = ldb(xin + (size_t)(pbase + mt*16 + lr)*256 + ks*32 + lg*8);
  const ffrag fz = {0.f,0.f,0.f,0.f};
  ffrag acc[2][2];
  acc[0][0]=fz; acc[0][1]=fz; acc[1][0]=fz; acc[1][1]=fz;
  #pragma unroll
  for (int nt=0; nt<2; ++nt)
    #pragma unroll
    for (int ks=0; ks<8; ++ks){
      bfrag b = ldb(wp + (size_t)(o0 + nsub + nt*16 + lr)*256 + ks*32 + lg*8);
      acc[0][nt] = MFMA16(a[0][ks], b, acc[0][nt]);
      acc[1][nt] = MFMA16(a[1][ks], b, acc[1][nt]);
    }
  #pragma unroll
  for (int nt=0; nt<2; ++nt){
    int oo = o0 + nsub + nt*16 + lr;
    float bs = bias[oo];
    #pragma unroll
    for (int mt=0; mt<2; ++mt){
      int pr = pbase + mt*16 + lg*4;
      #pragma unroll
      for (int r=0;r<4;++r)
        out[(size_t)(pr + r)*256 + oo] = f2bf(acc[mt][nt][r] + bs);
    }
  }
}

// ---------- BN stats over Vt (n,c,w): one block per channel; outputs a[c], b[c] ----------
__global__ __launch_bounds__(256) void k_vstats(const u16* __restrict__ Vt, const float* __restrict__ g,
                                                const float* __restrict__ be, float* __restrict__ aV,
                                                float* __restrict__ bV){
  int c = blockIdx.x, t = threadIdx.x;
  float s = 0.f, sq = 0.f;
  for (int n=0; n<128; ++n){
    const u16* rowp = Vt + ((size_t)(n*256 + c))*512;
    #pragma unroll
    for (int w0=0; w0<512; w0+=256){
      float v = bf2f(rowp[w0 + t]); s += v; sq += v*v;
    }
  }
  __shared__ float rs[256], rq[256];
  rs[t]=s; rq[t]=sq; __syncthreads();
  for (int st=128; st>0; st>>=1){ if (t<st){ rs[t]+=rs[t+st]; rq[t]+=rq[t+st]; } __syncthreads(); }
  if (t==0){
    float mean = rs[0]*(1.f/65536.f);
    float var  = rq[0]*(1.f/65536.f) - mean*mean;
    float aa = g[c]*rsqrtf(var + 1e-5f);
    aV[c]=aa; bV[c]=be[c]-aa*mean;
  }
}

// ---------- banded attention: block = (q-tile of 16, n) ; O = aV*(P*Vpre) + bV ----------
__global__ __launch_bounds__(256) void k_attn(const u16* __restrict__ Q, const u16* __restrict__ K,
    const u16* __restrict__ Vt, const float* __restrict__ aV, const float* __restrict__ bV,
    u16* __restrict__ O){
  __shared__ float Sld[16][516];
  __shared__ u16  Pld[16][520];
  int t = threadIdx.x, wid = t>>6, l = t&63, lr = l&15, lg = l>>4;
  int q0 = blockIdx.x*16, n = blockIdx.y;
  int lo = q0 - 132; if (lo < 0) lo = 0;
  int hi = q0 + 15 + 132; if (hi > 511) hi = 511;
  int ktlo = (lo >> 4) & ~1;     // even -> PV K-range 32-aligned
  int kthi = (hi >> 4) | 1;      // odd

  // Q A-frags hoisted (16 rows x 256 c)
  bfrag qa[8];
  #pragma unroll
  for (int ks=0; ks<8; ++ks)
    qa[ks] = ldb(Q + ((size_t)(n*512 + q0 + lr))*256 + ks*32 + lg*8);

  const ffrag fz = {0.f,0.f,0.f,0.f};
  // phase 1: S = Q*K^T over band tiles, elementwise mask
  for (int kt = ktlo + wid; kt <= kthi; kt += 4){
    ffrag acc = fz;
    #pragma unroll
    for (int ks=0; ks<8; ++ks){
      bfrag kbf = ldb(K + ((size_t)(n*512 + kt*16 + lr))*256 + ks*32 + lg*8);
      acc = MFMA16(qa[ks], kbf, acc);
    }
    int col = kt*16 + lr;
    #pragma unroll
    for (int r=0;r<4;++r){
      int row = lg*4 + r;
      int d = (q0 + row) - col;
      Sld[row][col] = (d < 133 && d > -133) ? acc[r] : -1e30f;
    }
  }
  __syncthreads();

  // phase 2: row softmax over [ktlo*16, (kthi+1)*16)
  {
    int row = t>>4, sub = t&15;
    int c_lo = ktlo*16, c_hi = (kthi+1)*16;
    float m = -1e30f;
    for (int c = c_lo + sub; c < c_hi; c += 16) m = fmaxf(m, Sld[row][c]);
    #pragma unroll
    for (int off=1; off<16; off<<=1) m = fmaxf(m, __shfl_xor(m, off, 64));
    float s = 0.f;
    for (int c = c_lo + sub; c < c_hi; c += 16){
      float e = __expf(Sld[row][c] - m);
      Sld[row][c] = e; s += e;
    }
    #pragma unroll
    for (int off=1; off<16; off<<=1) s += __shfl_xor(s, off, 64);
    float rinv = 1.f / s;
    for (int c = c_lo + sub; c < c_hi; c += 16)
      Pld[row][c] = f2bf(Sld[row][c] * rinv);
  }
  __syncthreads();

  // phase 3: O = P * Vpre ; epilogue applies folded BN (softmax rows sum to 1)
  int nk = (kthi + 1 - ktlo) >> 1;      // K-steps of 32
  for (int ct = wid; ct < 16; ct += 4){
    int c0 = ct*16;
    ffrag acc = fz;
    for (int ks=0; ks<nk; ++ks){
      int k0 = ktlo*16 + ks*32;
      bfrag pa = ldb(&Pld[lr][k0 + lg*8]);
      bfrag vbf = ldb(Vt + ((size_t)(n*256 + c0 + lr))*512 + k0 + lg*8);
      acc = MFMA16(pa, vbf, acc);
    }
    int cc = c0 + lr;
    float av = aV[cc], bv = bV[cc];
    #pragma unroll
    for (int r=0;r<4;++r){
      int qi = q0 + lg*4 + r;
      O[((size_t)(n*512 + qi))*256 + cc] = f2bf(av*acc[r] + bv);
    }
  }
}

// ---------- BN stats for u (p,c): stage 1 partials (256 blocks) ----------
__global__ __launch_bounds__(256) void k_ustat1(const u16* __restrict__ u, float* __restrict__ psum,
                                                float* __restrict__ psq){
  int bi = blockIdx.x, t = threadIdx.x;
  const u16* base = u + (size_t)bi*65536 + t;
  float s=0.f, sq=0.f;
  for (int r=0;r<256;++r){ float v = bf2f(base[(size_t)r*256]); s+=v; sq+=v*v; }
  psum[bi*256+t]=s; psq[bi*256+t]=sq;
}
// ---------- stage 2 reduce -> aW, bW ----------
__global__ __launch_bounds__(256) void k_ustat2(const float* __restrict__ psum, const float* __restrict__ psq,
                                                const float* __restrict__ g, const float* __restrict__ be,
                                                float* __restrict__ aW, float* __restrict__ bW){
  int c = threadIdx.x;
  float s=0.f, sq=0.f;
  for (int bi=0;bi<256;++bi){ s += psum[bi*256+c]; sq += psq[bi*256+c]; }
  float mean = s*(1.f/65536.f);
  float var  = sq*(1.f/65536.f) - mean*mean;
  float aa = g[c]*rsqrtf(var + 1e-5f);
  aW[c]=aa; bW[c]=be[c]-aa*mean;
}

// ---------- final: z[b,c,h,w] = aW*u[p,c] + bW + x[b,c,h,w] (LDS transpose) ----------
__global__ __launch_bounds__(256) void k_final(const u16* __restrict__ u, const float* __restrict__ x,
                                               const float* __restrict__ aW, const float* __restrict__ bW,
                                               float* __restrict__ z){
  __shared__ float T[64][65];
  typedef u16 us4 __attribute__((ext_vector_type(4)));
  int t = threadIdx.x;
  int p0 = blockIdx.x*64, c0 = blockIdx.y*64;
  int b = p0>>15, q0 = p0&32767;
  #pragma unroll
  for (int it=0; it<4; ++it){
    int pi = it*16 + (t>>4);
    int cj = (t&15)*4;
    us4 v; __builtin_memcpy(&v, u + (size_t)(p0+pi)*256 + c0 + cj, 8);
    #pragma unroll
    for (int j=0;j<4;++j) T[pi][cj+j] = bf2f(v[j]);
  }
  __syncthreads();
  #pragma unroll
  for (int it=0; it<16; ++it){
    int cc = it*4 + (t>>6);
    int qi = t&63;
    size_t addr = ((size_t)(b*256 + c0 + cc))*32768 + q0 + qi;
    z[addr] = aW[c0+cc]*T[qi][cc] + bW[c0+cc] + x[addr];
  }
}

extern "C" void kernel_launch(void* const* d_in, const int* in_sizes, int n_in,
                              void* d_out, int out_size, void* d_ws, size_t ws_size,
                              hipStream_t stream) {
  const float* x1  = (const float*)d_in[0];
  const float* x2  = (const float*)d_in[1];
  const float* Qw  = (const float*)d_in[2];
  const float* Qb  = (const float*)d_in[3];
  const float* Kw  = (const float*)d_in[4];
  const float* Kb  = (const float*)d_in[5];
  const float* Vw  = (const float*)d_in[6];
  const float* Vb  = (const float*)d_in[7];
  const float* Vg  = (const float*)d_in[8];
  const float* Vbe = (const float*)d_in[9];
  const float* Ww  = (const float*)d_in[10];
  const float* Wb  = (const float*)d_in[11];
  const float* Wg  = (const float*)d_in[12];
  const float* Wbe = (const float*)d_in[13];

  char* ws = (char*)d_ws;
  const size_t S = 33554432;                  // one (65536 x 256) bf16 slot = 32 MB
  u16* xr1 = (u16*)(ws + 0*S);                // later reused as O1
  u16* xr2 = (u16*)(ws + 1*S);                // later reused as O2
  u16* Q1  = (u16*)(ws + 2*S);                // later reused as u1
  u16* K1  = (u16*)(ws + 3*S);                // later reused as u2
  u16* Q2  = (u16*)(ws + 4*S);
  u16* K2  = (u16*)(ws + 5*S);
  u16* wb  = (u16*)(ws + 6*S);                // 4 x 65536 bf16
  float* vec = (float*)(ws + 6*S + 524288);
  float* aV1 = vec+0,   *bV1 = vec+256, *aV2 = vec+512,  *bV2 = vec+768;
  float* aW1 = vec+1024, *bW1 = vec+1280, *aW2 = vec+1536, *bW2 = vec+1792;
  float* psum = vec + 2048;                   // 65536 floats
  float* psq  = psum + 65536;                 // 65536 floats

  u16* Vt1 = (u16*)d_out;                     // d_out as scratch (dead before z writes)
  u16* Vt2 = (u16*)((char*)d_out + S);
  u16* O1 = xr1; u16* O2 = xr2;
  u16* u1 = Q1;  u16* u2 = K1;
  float* z = (float*)d_out;

  dim3 g1(1024, 4);
  dim3 ga(32, 128);

  k_wcvt<<<256, 256, 0, stream>>>(Qw, Kw, Vw, Ww, wb);
  k_xpose<<<g1, 256, 0, stream>>>(x1, xr1);
  k_xpose<<<g1, 256, 0, stream>>>(x2, xr2);
  k_qkv<<<g1, 256, 0, stream>>>(xr1, wb, Qb, Kb, Vb, Q1, K1, Vt1);
  k_qkv<<<g1, 256, 0, stream>>>(xr2, wb, Qb, Kb, Vb, Q2, K2, Vt2);
  k_vstats<<<256, 256, 0, stream>>>(Vt1, Vg, Vbe, aV1, bV1);
  k_vstats<<<256, 256, 0, stream>>>(Vt2, Vg, Vbe, aV2, bV2);
  k_attn<<<ga, 256, 0, stream>>>(Q1, K2, Vt2, aV2, bV2, O1);   // y1 = attend(q1,k2,v2)
  k_attn<<<ga, 256, 0, stream>>>(Q2, K1, Vt1, aV1, bV1, O2);   // y2 = attend(q2,k1,v1)
  k_conv1<<<g1, 256, 0, stream>>>(O1, wb + 196608, Wb, u1);
  k_conv1<<<g1, 256, 0, stream>>>(O2, wb + 196608, Wb, u2);
  k_ustat1<<<256, 256, 0, stream>>>(u1, psum, psq);
  k_ustat2<<<1, 256, 0, stream>>>(psum, psq, Wg, Wbe, aW1, bW1);
  k_ustat1<<<256, 256, 0, stream>>>(u2, psum, psq);
  k_ustat2<<<1, 256, 0, stream>>>(psum, psq, Wg, Wbe, aW2, bW2);
  k_final<<<g1, 256, 0, stream>>>(u1, x1, aW1, bW1, z);
  k_final<<<g1, 256, 0, stream>>>(u2, x2, aW2, bW2, z + 16777216);
}

// Round 2
// 826.106 us; speedup vs baseline: 1.0988x; 1.0988x over previous
//
#include <hip/hip_runtime.h>

typedef unsigned short u16;
typedef short bfrag __attribute__((ext_vector_type(8)));   // 8 bf16 = one MFMA A/B frag
typedef float ffrag __attribute__((ext_vector_type(4)));   // MFMA C/D frag
typedef u16 u16x4 __attribute__((ext_vector_type(4)));

#define MFMA16(a,b,c) __builtin_amdgcn_mfma_f32_16x16x32_bf16((a),(b),(c),0,0,0)

// B=2, C=256, H=64, W=512 ; PIX=65536 ; NROW=B*H=128 ; max_w=int(512*0.26)=133 -> |i-j|<=132

__device__ __forceinline__ u16 f2bf(float f){
  union { float f; unsigned int i; } cv; cv.f = f;
  unsigned int x = cv.i;
  return (u16)((x + 0x7fffu + ((x >> 16) & 1u)) >> 16);  // RNE
}
__device__ __forceinline__ float bf2f(u16 u){
  union { unsigned int i; float f; } cv;
  cv.i = ((unsigned int)u) << 16;
  return cv.f;
}
__device__ __forceinline__ bfrag ldb(const u16* p){
  bfrag v; __builtin_memcpy(&v, p, 16); return v;
}

// ---------- weights fp32 -> bf16 ----------
__global__ __launch_bounds__(256) void k_wcvt(const float* __restrict__ qw, const float* __restrict__ kw,
                                              const float* __restrict__ vw, const float* __restrict__ ww,
                                              u16* __restrict__ out){
  int t = blockIdx.x*256 + threadIdx.x;
  out[t]        = f2bf(qw[t]);
  out[t+65536]  = f2bf(kw[t]);
  out[t+131072] = f2bf(vw[t]);
  out[t+196608] = f2bf(ww[t]);
}

// ---------- x (B,C,H,W) fp32 -> xr (p, c) bf16 ----------
__global__ __launch_bounds__(256) void k_xpose(const float* __restrict__ x, u16* __restrict__ xr){
  __shared__ float T[64][65];
  int t = threadIdx.x;
  int p0 = blockIdx.x*64, c0 = blockIdx.y*64;
  int b = p0 >> 15, q0 = p0 & 32767;
  #pragma unroll
  for (int it=0; it<4; ++it){
    int cc = it*16 + (t>>4);
    int pi = (t&15)*4;
    ffrag v; __builtin_memcpy(&v, x + ((size_t)(b*256 + c0 + cc))*32768 + q0 + pi, 16);
    T[cc][pi+0]=v[0]; T[cc][pi+1]=v[1]; T[cc][pi+2]=v[2]; T[cc][pi+3]=v[3];
  }
  __syncthreads();
  int pi = t>>2, cj0 = (t&3)*16;
  u16 tmp[16];
  #pragma unroll
  for (int j=0;j<16;++j) tmp[j] = f2bf(T[cj0+j][pi]);
  __builtin_memcpy(xr + (size_t)(p0+pi)*256 + c0 + cj0, tmp, 32);
}

// ---------- QKV conv: block = 64p x 256o, wave = 32p x 128o; xr read ONCE ----------
__global__ __launch_bounds__(256) void k_qkv(const u16* __restrict__ xr, const u16* __restrict__ wb,
    const float* __restrict__ qb, const float* __restrict__ kb, const float* __restrict__ vb,
    u16* __restrict__ Qo, u16* __restrict__ Ko, u16* __restrict__ Vt){
  int t = threadIdx.x, wid = t>>6, l = t&63, lr = l&15, lg = l>>4;
  int p0 = blockIdx.x*64;
  int msub = (wid&1)*32, osub = (wid>>1)*128;
  int pbase = p0 + msub;

  bfrag a[2][8];
  #pragma unroll
  for (int mt=0; mt<2; ++mt)
    #pragma unroll
    for (int ks=0; ks<8; ++ks)
      a[mt][ks] = ldb(xr + (size_t)(pbase + mt*16 + lr)*256 + ks*32 + lg*8);

  const ffrag fz = {0.f,0.f,0.f,0.f};
  #pragma unroll
  for (int wgt=0; wgt<3; ++wgt){
    const u16* wp = wb + wgt*65536;
    const float* bias = (wgt==0)? qb : (wgt==1)? kb : vb;
    #pragma unroll
    for (int nt=0; nt<8; ++nt){
      int o0 = osub + nt*16;
      ffrag acc0 = fz, acc1 = fz;
      #pragma unroll
      for (int ks=0; ks<8; ++ks){
        bfrag b = ldb(wp + (size_t)(o0 + lr)*256 + ks*32 + lg*8);
        acc0 = MFMA16(a[0][ks], b, acc0);
        acc1 = MFMA16(a[1][ks], b, acc1);
      }
      int oo = o0 + lr;
      float bs = bias[oo];
      #pragma unroll
      for (int mt=0; mt<2; ++mt){
        ffrag acc = mt ? acc1 : acc0;
        int pr = pbase + mt*16 + lg*4;
        if (wgt == 2){
          int n = pr >> 9, w0 = pr & 511;
          u16x4 vv;
          #pragma unroll
          for (int r=0;r<4;++r) vv[r] = f2bf(acc[r] + bs);
          *reinterpret_cast<u16x4*>(Vt + ((size_t)(n*256 + oo))*512 + w0) = vv;
        } else {
          u16* op = (wgt==0)? Qo : Ko;
          #pragma unroll
          for (int r=0;r<4;++r)
            op[(size_t)(pr + r)*256 + oo] = f2bf(acc[r] + bs);
        }
      }
    }
  }
}

// ---------- W conv: block = 64p x 256o ----------
__global__ __launch_bounds__(256) void k_conv1(const u16* __restrict__ xin, const u16* __restrict__ wp,
    const float* __restrict__ bias, u16* __restrict__ out){
  int t = threadIdx.x, wid = t>>6, l = t&63, lr = l&15, lg = l>>4;
  int p0 = blockIdx.x*64;
  int msub = (wid&1)*32, osub = (wid>>1)*128;
  int pbase = p0 + msub;
  bfrag a[2][8];
  #pragma unroll
  for (int mt=0; mt<2; ++mt)
    #pragma unroll
    for (int ks=0; ks<8; ++ks)
      a[mt][ks] = ldb(xin + (size_t)(pbase + mt*16 + lr)*256 + ks*32 + lg*8);
  const ffrag fz = {0.f,0.f,0.f,0.f};
  #pragma unroll
  for (int nt=0; nt<8; ++nt){
    int o0 = osub + nt*16;
    ffrag acc0 = fz, acc1 = fz;
    #pragma unroll
    for (int ks=0; ks<8; ++ks){
      bfrag b = ldb(wp + (size_t)(o0 + lr)*256 + ks*32 + lg*8);
      acc0 = MFMA16(a[0][ks], b, acc0);
      acc1 = MFMA16(a[1][ks], b, acc1);
    }
    int oo = o0 + lr;
    float bs = bias[oo];
    #pragma unroll
    for (int mt=0; mt<2; ++mt){
      ffrag acc = mt ? acc1 : acc0;
      int pr = pbase + mt*16 + lg*4;
      #pragma unroll
      for (int r=0;r<4;++r)
        out[(size_t)(pr + r)*256 + oo] = f2bf(acc[r] + bs);
    }
  }
}

// ---------- V BN stats, two-stage ----------
__global__ __launch_bounds__(256) void k_vstat1(const u16* __restrict__ Vt, float* __restrict__ ps,
                                                float* __restrict__ pq){
  int c = blockIdx.x, ch = blockIdx.y, t = threadIdx.x;
  float s=0.f, sq=0.f;
  for (int nn=0; nn<16; ++nn){
    const u16* row = Vt + ((size_t)((ch*16+nn)*256 + c))*512 + t;
    float v = bf2f(row[0]);   s+=v; sq+=v*v;
    v = bf2f(row[256]);       s+=v; sq+=v*v;
  }
  __shared__ float rs[256], rq[256];
  rs[t]=s; rq[t]=sq; __syncthreads();
  for (int st=128; st>0; st>>=1){ if (t<st){ rs[t]+=rs[t+st]; rq[t]+=rq[t+st]; } __syncthreads(); }
  if (t==0){ ps[c*8+ch]=rs[0]; pq[c*8+ch]=rq[0]; }
}
__global__ __launch_bounds__(256) void k_vstat2(const float* __restrict__ ps, const float* __restrict__ pq,
                                                const float* __restrict__ g, const float* __restrict__ be,
                                                float* __restrict__ aV, float* __restrict__ bV){
  int c = threadIdx.x;
  float s=0.f, sq=0.f;
  #pragma unroll
  for (int ch=0; ch<8; ++ch){ s += ps[c*8+ch]; sq += pq[c*8+ch]; }
  float mean = s*(1.f/65536.f);
  float var  = sq*(1.f/65536.f) - mean*mean;
  float aa = g[c]*rsqrtf(var + 1e-5f);
  aV[c]=aa; bV[c]=be[c]-aa*mean;
}

// ---------- banded attention v2: QBLK=64, per-wave 16-row strip, NO barriers ----------
// S in registers via swapped mfma(K,Q); in-lane softmax; P via per-wave XOR-swizzled LDS.
__global__ __launch_bounds__(256) void k_attn(const u16* __restrict__ Q, const u16* __restrict__ K,
    const u16* __restrict__ Vt, const float* __restrict__ aV, const float* __restrict__ bV,
    u16* __restrict__ O){
  __shared__ u16 PT[4][16][320];                 // per-wave P rows; row stride 640B
  int t = threadIdx.x, wid = t>>6, l = t&63, lr = l&15, lg = l>>4;
  int id = blockIdx.x;
  int xcd = id & 7, s5 = id >> 3;
  int qb = s5 & 7, n = (xcd<<4) | (s5>>3);       // same-n blocks co-located per XCD
  int q0w = qb*64 + wid*16;
  int lo = q0w - 132; if (lo < 0) lo = 0;
  int hi = q0w + 147; if (hi > 511) hi = 511;
  int ktlo = (lo >> 4) & ~1;                     // even -> 32-aligned PV window
  int kthi = (hi >> 4) | 1;                      // odd

  // Q B-frags for this strip (rows q0w..q0w+15)
  bfrag qa[8];
  const u16* Qrow = Q + ((size_t)(n*512 + q0w + lr))*256 + lg*8;
  #pragma unroll
  for (int ks=0; ks<8; ++ks) qa[ks] = ldb(Qrow + ks*32);

  const ffrag fz = {0.f,0.f,0.f,0.f};
  ffrag acc[20];
  #pragma unroll
  for (int i=0;i<20;++i) acc[i] = fz;

  // phase 1: S^T tiles = mfma(K, Q) -> lane holds S[q0w+lr][(ktlo+i)*16 + lg*4 + r]
  const u16* Kbase = K + ((size_t)n*512)*256;
  #pragma unroll
  for (int i=0;i<20;++i){
    int kt = ktlo + i;
    if (kt <= kthi){
      const u16* Krow = Kbase + (size_t)(kt*16 + lr)*256 + lg*8;
      #pragma unroll
      for (int ks=0; ks<8; ++ks)
        acc[i] = MFMA16(ldb(Krow + ks*32), qa[ks], acc[i]);
    }
  }

  // phase 2: in-register softmax (row q = q0w+lr, values spread over lg via xor 16/32)
  int q = q0w + lr;
  float m = -1e30f;
  #pragma unroll
  for (int i=0;i<20;++i){
    int colb = (ktlo+i)*16 + lg*4;
    #pragma unroll
    for (int r=0;r<4;++r){
      int col = colb + r;
      int d = q - col;
      bool v = (d < 133) && (d > -133) && (col < 512);
      m = v ? fmaxf(m, acc[i][r]) : m;
    }
  }
  m = fmaxf(m, __shfl_xor(m, 16, 64));
  m = fmaxf(m, __shfl_xor(m, 32, 64));
  float sum = 0.f;
  #pragma unroll
  for (int i=0;i<20;++i){
    int colb = (ktlo+i)*16 + lg*4;
    #pragma unroll
    for (int r=0;r<4;++r){
      int col = colb + r;
      int d = q - col;
      bool v = (d < 133) && (d > -133) && (col < 512);
      float e = v ? __expf(acc[i][r] - m) : 0.f;
      acc[i][r] = e; sum += e;
    }
  }
  sum += __shfl_xor(sum, 16, 64);
  sum += __shfl_xor(sum, 32, 64);
  float rinv = 1.f / sum;

  // write P (bf16) to per-wave LDS, XOR-swizzled: byte ^= (row&7)<<4
  char* PTw = (char*)&PT[wid][0][0];
  #pragma unroll
  for (int i=0;i<20;++i){
    u16x4 pv;
    #pragma unroll
    for (int r=0;r<4;++r) pv[r] = f2bf(acc[i][r]*rinv);
    int boff = (i*32 + lg*8) ^ ((lr&7)<<4);
    *reinterpret_cast<u16x4*>(PTw + lr*640 + boff) = pv;
  }
  asm volatile("" ::: "memory");                 // order ds_reads after ds_writes (same wave)

  // phase 3: O = P*Vpre with folded-BN epilogue
  int nk = (kthi + 1 - ktlo) >> 1;
  bfrag pa[10];
  #pragma unroll
  for (int ks=0; ks<10; ++ks)
    if (ks < nk){
      int boff = (ks*64 + lg*16) ^ ((lr&7)<<4);
      pa[ks] = *reinterpret_cast<const bfrag*>(PTw + lr*640 + boff);
    }

  const u16* Vbase = Vt + (size_t)n*131072 + ktlo*16 + lg*8;
  #pragma unroll
  for (int cg=0; cg<4; ++cg){
    ffrag o[4] = {fz,fz,fz,fz};
    #pragma unroll
    for (int ks=0; ks<10; ++ks)
      if (ks < nk){
        #pragma unroll
        for (int cc=0; cc<4; ++cc){
          int c = (cg*4+cc)*16 + lr;
          bfrag vbf = ldb(Vbase + (size_t)c*512 + ks*32);
          o[cc] = MFMA16(pa[ks], vbf, o[cc]);
        }
      }
    #pragma unroll
    for (int cc=0; cc<4; ++cc){
      int c = (cg*4+cc)*16 + lr;
      float av = aV[c], bv = bV[c];
      #pragma unroll
      for (int r=0;r<4;++r)
        O[((size_t)(n*512 + q0w + lg*4 + r))*256 + c] = f2bf(av*o[cc][r] + bv);
    }
  }
}

// ---------- u BN stats, two-stage (1024 partials) ----------
__global__ __launch_bounds__(256) void k_ustat1(const u16* __restrict__ u, float* __restrict__ psum,
                                                float* __restrict__ psq){
  int bi = blockIdx.x, t = threadIdx.x;
  const u16* base = u + (size_t)bi*16384 + t;    // 64 rows x 256 c
  float s=0.f, sq=0.f;
  #pragma unroll 4
  for (int r=0;r<64;++r){ float v = bf2f(base[r*256]); s+=v; sq+=v*v; }
  psum[t*1024 + bi] = s; psq[t*1024 + bi] = sq;
}
__global__ __launch_bounds__(256) void k_ustat2(const float* __restrict__ psum, const float* __restrict__ psq,
                                                const float* __restrict__ g, const float* __restrict__ be,
                                                float* __restrict__ aW, float* __restrict__ bW){
  int c = blockIdx.x, t = threadIdx.x;
  float s=0.f, sq=0.f;
  #pragma unroll
  for (int j=0;j<4;++j){ s += psum[(size_t)c*1024 + t + j*256]; sq += psq[(size_t)c*1024 + t + j*256]; }
  __shared__ float rs[256], rq[256];
  rs[t]=s; rq[t]=sq; __syncthreads();
  for (int st=128; st>0; st>>=1){ if (t<st){ rs[t]+=rs[t+st]; rq[t]+=rq[t+st]; } __syncthreads(); }
  if (t==0){
    float mean = rs[0]*(1.f/65536.f);
    float var  = rq[0]*(1.f/65536.f) - mean*mean;
    float aa = g[c]*rsqrtf(var + 1e-5f);
    aW[c]=aa; bW[c]=be[c]-aa*mean;
  }
}

// ---------- final: z = aW*u + bW + x (transpose back to (B,C,H,W)) ----------
__global__ __launch_bounds__(256) void k_final(const u16* __restrict__ u, const float* __restrict__ x,
                                               const float* __restrict__ aW, const float* __restrict__ bW,
                                               float* __restrict__ z){
  __shared__ float T[64][65];
  int t = threadIdx.x;
  int p0 = blockIdx.x*64, c0 = blockIdx.y*64;
  int b = p0>>15, q0 = p0&32767;
  #pragma unroll
  for (int it=0; it<4; ++it){
    int pi = it*16 + (t>>4);
    int cj = (t&15)*4;
    u16x4 v; __builtin_memcpy(&v, u + (size_t)(p0+pi)*256 + c0 + cj, 8);
    #pragma unroll
    for (int j=0;j<4;++j) T[pi][cj+j] = bf2f(v[j]);
  }
  __syncthreads();
  #pragma unroll
  for (int it=0; it<16; ++it){
    int cc = it*4 + (t>>6);
    int qi = t&63;
    size_t addr = ((size_t)(b*256 + c0 + cc))*32768 + q0 + qi;
    z[addr] = aW[c0+cc]*T[qi][cc] + bW[c0+cc] + x[addr];
  }
}

extern "C" void kernel_launch(void* const* d_in, const int* in_sizes, int n_in,
                              void* d_out, int out_size, void* d_ws, size_t ws_size,
                              hipStream_t stream) {
  const float* x1  = (const float*)d_in[0];
  const float* x2  = (const float*)d_in[1];
  const float* Qw  = (const float*)d_in[2];
  const float* Qb  = (const float*)d_in[3];
  const float* Kw  = (const float*)d_in[4];
  const float* Kb  = (const float*)d_in[5];
  const float* Vw  = (const float*)d_in[6];
  const float* Vb  = (const float*)d_in[7];
  const float* Vg  = (const float*)d_in[8];
  const float* Vbe = (const float*)d_in[9];
  const float* Ww  = (const float*)d_in[10];
  const float* Wb  = (const float*)d_in[11];
  const float* Wg  = (const float*)d_in[12];
  const float* Wbe = (const float*)d_in[13];

  char* ws = (char*)d_ws;
  const size_t S = 33554432;                  // one (65536 x 256) bf16 slot = 32 MB
  u16* xr1 = (u16*)(ws + 0*S);                // later reused as O1
  u16* xr2 = (u16*)(ws + 1*S);                // later reused as O2
  u16* Q1  = (u16*)(ws + 2*S);                // later reused as u1
  u16* K1  = (u16*)(ws + 3*S);                // later reused as u2
  u16* Q2  = (u16*)(ws + 4*S);
  u16* K2  = (u16*)(ws + 5*S);
  u16* wb  = (u16*)(ws + 6*S);                // 4 x 65536 bf16
  float* vec = (float*)(ws + 6*S + 524288);
  float* aV1 = vec+0,    *bV1 = vec+256,  *aV2 = vec+512,  *bV2 = vec+768;
  float* aW1 = vec+1024, *bW1 = vec+1280, *aW2 = vec+1536, *bW2 = vec+1792;
  float* psum = vec + 2048;                   // 262144 floats (1 MB)
  float* psq  = psum + 262144;                // 262144 floats

  u16* Vt1 = (u16*)d_out;                     // d_out as scratch (dead before z writes)
  u16* Vt2 = (u16*)((char*)d_out + S);
  u16* O1 = xr1; u16* O2 = xr2;
  u16* u1 = Q1;  u16* u2 = K1;
  float* z = (float*)d_out;

  dim3 g1(1024, 4);
  dim3 gv(256, 8);

  k_wcvt<<<256, 256, 0, stream>>>(Qw, Kw, Vw, Ww, wb);
  k_xpose<<<g1, 256, 0, stream>>>(x1, xr1);
  k_xpose<<<g1, 256, 0, stream>>>(x2, xr2);
  k_qkv<<<1024, 256, 0, stream>>>(xr1, wb, Qb, Kb, Vb, Q1, K1, Vt1);
  k_qkv<<<1024, 256, 0, stream>>>(xr2, wb, Qb, Kb, Vb, Q2, K2, Vt2);
  k_vstat1<<<gv, 256, 0, stream>>>(Vt1, psum, psq);
  k_vstat2<<<1, 256, 0, stream>>>(psum, psq, Vg, Vbe, aV1, bV1);
  k_vstat1<<<gv, 256, 0, stream>>>(Vt2, psum, psq);
  k_vstat2<<<1, 256, 0, stream>>>(psum, psq, Vg, Vbe, aV2, bV2);
  k_attn<<<1024, 256, 0, stream>>>(Q1, K2, Vt2, aV2, bV2, O1);   // y1 = attend(q1,k2,v2)
  k_attn<<<1024, 256, 0, stream>>>(Q2, K1, Vt1, aV1, bV1, O2);   // y2 = attend(q2,k1,v1)
  k_conv1<<<1024, 256, 0, stream>>>(O1, wb + 196608, Wb, u1);
  k_conv1<<<1024, 256, 0, stream>>>(O2, wb + 196608, Wb, u2);
  k_ustat1<<<1024, 256, 0, stream>>>(u1, psum, psq);
  k_ustat2<<<256, 256, 0, stream>>>(psum, psq, Wg, Wbe, aW1, bW1);
  k_ustat1<<<1024, 256, 0, stream>>>(u2, psum, psq);
  k_ustat2<<<256, 256, 0, stream>>>(psum, psq, Wg, Wbe, aW2, bW2);
  k_final<<<g1, 256, 0, stream>>>(u1, x1, aW1, bW1, z);
  k_final<<<g1, 256, 0, stream>>>(u2, x2, aW2, bW2, z + 16777216);
}

// Round 3
// 555.874 us; speedup vs baseline: 1.6330x; 1.4861x over previous
//
#include <hip/hip_runtime.h>

typedef unsigned short u16;
typedef short bfrag __attribute__((ext_vector_type(8)));   // 8 bf16 = one MFMA A/B frag
typedef float ffrag __attribute__((ext_vector_type(4)));   // MFMA C/D frag
typedef u16 u16x4 __attribute__((ext_vector_type(4)));

#define MFMA16(a,b,c) __builtin_amdgcn_mfma_f32_16x16x32_bf16((a),(b),(c),0,0,0)

// B=2, C=256, H=64, W=512 ; PIX=65536 ; NROW=B*H=128 ; max_w=int(512*0.26)=133 -> |i-j|<=132

__device__ __forceinline__ u16 f2bf(float f){
  union { float f; unsigned int i; } cv; cv.f = f;
  unsigned int x = cv.i;
  return (u16)((x + 0x7fffu + ((x >> 16) & 1u)) >> 16);  // RNE
}
__device__ __forceinline__ float bf2f(u16 u){
  union { unsigned int i; float f; } cv;
  cv.i = ((unsigned int)u) << 16;
  return cv.f;
}
__device__ __forceinline__ bfrag ldb(const u16* p){
  bfrag v; __builtin_memcpy(&v, p, 16); return v;
}
__device__ __forceinline__ void gload_lds16(const u16* g, u16* l){
  __builtin_amdgcn_global_load_lds(
      (const __attribute__((address_space(1))) unsigned int*)g,
      (__attribute__((address_space(3))) unsigned int*)l, 16, 0, 0);
}

// ---------- weights fp32 -> bf16 ----------
__global__ __launch_bounds__(256) void k_wcvt(const float* __restrict__ qw, const float* __restrict__ kw,
                                              const float* __restrict__ vw, const float* __restrict__ ww,
                                              u16* __restrict__ out){
  int t = blockIdx.x*256 + threadIdx.x;
  out[t]        = f2bf(qw[t]);
  out[t+65536]  = f2bf(kw[t]);
  out[t+131072] = f2bf(vw[t]);
  out[t+196608] = f2bf(ww[t]);
}

// ---------- x (B,C,H,W) fp32 -> xr (p, c) bf16 ; fused both streams via z ----------
__global__ __launch_bounds__(256) void k_xpose(const float* __restrict__ x1, const float* __restrict__ x2,
                                               u16* __restrict__ xr1, u16* __restrict__ xr2){
  const float* x = blockIdx.z ? x2 : x1;
  u16* xr = blockIdx.z ? xr2 : xr1;
  __shared__ float T[64][65];
  int t = threadIdx.x;
  int p0 = blockIdx.x*64, c0 = blockIdx.y*64;
  int b = p0 >> 15, q0 = p0 & 32767;
  #pragma unroll
  for (int it=0; it<4; ++it){
    int cc = it*16 + (t>>4);
    int pi = (t&15)*4;
    ffrag v; __builtin_memcpy(&v, x + ((size_t)(b*256 + c0 + cc))*32768 + q0 + pi, 16);
    T[cc][pi+0]=v[0]; T[cc][pi+1]=v[1]; T[cc][pi+2]=v[2]; T[cc][pi+3]=v[3];
  }
  __syncthreads();
  int pi = t>>2, cj0 = (t&3)*16;
  u16 tmp[16];
  #pragma unroll
  for (int j=0;j<16;++j) tmp[j] = f2bf(T[cj0+j][pi]);
  __builtin_memcpy(xr + (size_t)(p0+pi)*256 + c0 + cj0, tmp, 32);
}

// ---------- QKV conv: ks-outer (batched B loads); fused streams via z ----------
__global__ __launch_bounds__(256, 2) void k_qkv(const u16* __restrict__ xr1, const u16* __restrict__ xr2,
    const u16* __restrict__ wb,
    const float* __restrict__ qb, const float* __restrict__ kb, const float* __restrict__ vb,
    u16* __restrict__ Q1, u16* __restrict__ K1, u16* __restrict__ V1,
    u16* __restrict__ Q2, u16* __restrict__ K2, u16* __restrict__ V2){
  int s = blockIdx.z;
  const u16* xr = s ? xr2 : xr1;
  u16* Qo = s ? Q2 : Q1;  u16* Ko = s ? K2 : K1;  u16* Vt = s ? V2 : V1;

  int t = threadIdx.x, wid = t>>6, l = t&63, lr = l&15, lg = l>>4;
  int p0 = blockIdx.x*64;
  int msub = (wid&1)*32, osub = (wid>>1)*128;
  int pbase = p0 + msub;

  bfrag a[2][8];
  #pragma unroll
  for (int mt=0; mt<2; ++mt)
    #pragma unroll
    for (int ks=0; ks<8; ++ks)
      a[mt][ks] = ldb(xr + (size_t)(pbase + mt*16 + lr)*256 + ks*32 + lg*8);

  const ffrag fz = {0.f,0.f,0.f,0.f};
  #pragma unroll
  for (int wgt=0; wgt<3; ++wgt){
    const u16* wp = wb + wgt*65536;
    const float* bias = (wgt==0)? qb : (wgt==1)? kb : vb;
    ffrag acc[2][8];
    #pragma unroll
    for (int nt=0; nt<8; ++nt){ acc[0][nt]=fz; acc[1][nt]=fz; }
    #pragma unroll
    for (int ks=0; ks<8; ++ks){
      bfrag b[8];
      #pragma unroll
      for (int nt=0; nt<8; ++nt)
        b[nt] = ldb(wp + (size_t)(osub + nt*16 + lr)*256 + ks*32 + lg*8);
      #pragma unroll
      for (int nt=0; nt<8; ++nt){
        acc[0][nt] = MFMA16(a[0][ks], b[nt], acc[0][nt]);
        acc[1][nt] = MFMA16(a[1][ks], b[nt], acc[1][nt]);
      }
    }
    #pragma unroll
    for (int nt=0; nt<8; ++nt){
      int oo = osub + nt*16 + lr;
      float bs = bias[oo];
      #pragma unroll
      for (int mt=0; mt<2; ++mt){
        int pr = pbase + mt*16 + lg*4;
        if (wgt == 2){
          int n = pr >> 9, w0 = pr & 511;
          u16x4 vv;
          #pragma unroll
          for (int r=0;r<4;++r) vv[r] = f2bf(acc[mt][nt][r] + bs);
          *reinterpret_cast<u16x4*>(Vt + ((size_t)(n*256 + oo))*512 + w0) = vv;
        } else {
          u16* op = (wgt==0)? Qo : Ko;
          #pragma unroll
          for (int r=0;r<4;++r)
            op[(size_t)(pr + r)*256 + oo] = f2bf(acc[mt][nt][r] + bs);
        }
      }
    }
  }
}

// ---------- W conv: ks-outer; fused streams ----------
__global__ __launch_bounds__(256, 2) void k_conv1(const u16* __restrict__ in1, const u16* __restrict__ in2,
    const u16* __restrict__ wp, const float* __restrict__ bias,
    u16* __restrict__ o1, u16* __restrict__ o2){
  int s = blockIdx.z;
  const u16* xin = s ? in2 : in1;
  u16* out = s ? o2 : o1;
  int t = threadIdx.x, wid = t>>6, l = t&63, lr = l&15, lg = l>>4;
  int p0 = blockIdx.x*64;
  int msub = (wid&1)*32, osub = (wid>>1)*128;
  int pbase = p0 + msub;
  bfrag a[2][8];
  #pragma unroll
  for (int mt=0; mt<2; ++mt)
    #pragma unroll
    for (int ks=0; ks<8; ++ks)
      a[mt][ks] = ldb(xin + (size_t)(pbase + mt*16 + lr)*256 + ks*32 + lg*8);
  const ffrag fz = {0.f,0.f,0.f,0.f};
  ffrag acc[2][8];
  #pragma unroll
  for (int nt=0; nt<8; ++nt){ acc[0][nt]=fz; acc[1][nt]=fz; }
  #pragma unroll
  for (int ks=0; ks<8; ++ks){
    bfrag b[8];
    #pragma unroll
    for (int nt=0; nt<8; ++nt)
      b[nt] = ldb(wp + (size_t)(osub + nt*16 + lr)*256 + ks*32 + lg*8);
    #pragma unroll
    for (int nt=0; nt<8; ++nt){
      acc[0][nt] = MFMA16(a[0][ks], b[nt], acc[0][nt]);
      acc[1][nt] = MFMA16(a[1][ks], b[nt], acc[1][nt]);
    }
  }
  #pragma unroll
  for (int nt=0; nt<8; ++nt){
    int oo = osub + nt*16 + lr;
    float bs = bias[oo];
    #pragma unroll
    for (int mt=0; mt<2; ++mt){
      int pr = pbase + mt*16 + lg*4;
      #pragma unroll
      for (int r=0;r<4;++r)
        out[(size_t)(pr + r)*256 + oo] = f2bf(acc[mt][nt][r] + bs);
    }
  }
}

// ---------- V BN stats, two-stage; fused streams ----------
__global__ __launch_bounds__(256) void k_vstat1(const u16* __restrict__ V1, const u16* __restrict__ V2,
                                                float* __restrict__ ps, float* __restrict__ pq){
  int s = blockIdx.z;
  const u16* Vt = s ? V2 : V1;
  int c = blockIdx.x, ch = blockIdx.y, t = threadIdx.x;
  float sm=0.f, sq=0.f;
  for (int nn=0; nn<16; ++nn){
    const u16* row = Vt + ((size_t)((ch*16+nn)*256 + c))*512 + t;
    float v = bf2f(row[0]);   sm+=v; sq+=v*v;
    v = bf2f(row[256]);       sm+=v; sq+=v*v;
  }
  __shared__ float rs[256], rq[256];
  rs[t]=sm; rq[t]=sq; __syncthreads();
  for (int st=128; st>0; st>>=1){ if (t<st){ rs[t]+=rs[t+st]; rq[t]+=rq[t+st]; } __syncthreads(); }
  if (t==0){ ps[s*2048 + c*8+ch]=rs[0]; pq[s*2048 + c*8+ch]=rq[0]; }
}
__global__ __launch_bounds__(256) void k_vstat2(const float* __restrict__ ps, const float* __restrict__ pq,
                                                const float* __restrict__ g, const float* __restrict__ be,
                                                float* __restrict__ aVall, float* __restrict__ bVall){
  int s = blockIdx.x, c = threadIdx.x;
  float sm=0.f, sq=0.f;
  #pragma unroll
  for (int ch=0; ch<8; ++ch){ sm += ps[s*2048 + c*8+ch]; sq += pq[s*2048 + c*8+ch]; }
  float mean = sm*(1.f/65536.f);
  float var  = sq*(1.f/65536.f) - mean*mean;
  float aa = g[c]*rsqrtf(var + 1e-5f);
  aVall[s*256+c]=aa; bVall[s*256+c]=be[c]-aa*mean;
}

// ---------- staging helpers for k_attn ----------
__device__ __forceinline__ void stageK(const u16* Kn, u16* kb, int kt, int wid, int l){
  #pragma unroll
  for (int c2=0; c2<2; ++c2){
    int off = wid*2048 + c2*1024 + l*16;            // byte offset in 8KB tile
    int row = off>>9, inb = off&511;
    int src = inb ^ ((row&7)<<4);                   // pre-swizzled source
    gload_lds16(Kn + (size_t)(kt*16+row)*256 + (src>>1), kb + wid*1024 + c2*512);
  }
}
__device__ __forceinline__ void stageV(const u16* Vn, u16* vb, int k0, int wid, int l){
  #pragma unroll
  for (int c4=0; c4<4; ++c4){
    int off = wid*4096 + c4*1024 + l*16;            // byte offset in 16KB tile
    int crow = off>>6, inb = off&63;
    gload_lds16(Vn + (size_t)crow*512 + k0 + (inb>>1), vb + wid*2048 + c4*512);
  }
}

// ---------- banded attention v3: block-uniform band, LDS-staged K/V, double-buffered ----------
__global__ __launch_bounds__(256, 2) void k_attn(
    const u16* __restrict__ Q1, const u16* __restrict__ K2, const u16* __restrict__ V2,
    const u16* __restrict__ Q2, const u16* __restrict__ K1, const u16* __restrict__ V1,
    const float* __restrict__ aVall, const float* __restrict__ bVall,
    u16* __restrict__ O1, u16* __restrict__ O2){
  __shared__ __align__(16) u16 PT[4][16][384];      // 48KB: per-wave P rows (768B stride, XOR-swz)
  __shared__ __align__(16) u16 SB[16384];           // 32KB: K dbuf (2x8KB) / V dbuf (2x16KB), phase-shared
  int t = threadIdx.x, wid = t>>6, l = t&63, lr = l&15, lg = l>>4;
  int id = blockIdx.x;
  int s = id >> 10;                                  // stream high-bit: XCD phases see one stream
  int r0 = id & 1023;
  int xcd = r0 & 7, s5 = r0 >> 3;
  int qb = s5 & 7, n = (xcd<<4) | (s5>>3);
  const u16* Q = s ? Q2 : Q1;
  const u16* K = s ? K1 : K2;
  const u16* V = s ? V1 : V2;
  const float* aV = aVall + (s ? 0 : 256);           // y1 uses V2's stats
  const float* bV = bVall + (s ? 0 : 256);
  u16* O = s ? O2 : O1;

  int q0 = qb*64, q0w = q0 + wid*16;
  int lo = q0 - 132; if (lo < 0) lo = 0;
  int hi = q0 + 195; if (hi > 511) hi = 511;
  int KTLO = (lo>>4) & ~1;                           // even
  int KTHI = (hi>>4) | 1;                            // odd
  int NT = KTHI - KTLO + 1;                          // even, <= 24

  const u16* Kn = K + (size_t)n*131072;
  const u16* Vn = V + (size_t)n*131072;

  stageK(Kn, &SB[0], KTLO, wid, l);                  // prologue stage tile 0

  // Q frags (16 rows x 256 c)
  bfrag qa[8];
  const u16* Qrow = Q + ((size_t)(n*512 + q0w + lr))*256 + lg*8;
  #pragma unroll
  for (int ks=0; ks<8; ++ks) qa[ks] = ldb(Qrow + ks*32);

  const ffrag fz = {0.f,0.f,0.f,0.f};
  ffrag acc[24];
  #pragma unroll
  for (int i=0;i<24;++i) acc[i] = fz;

  // phase 1: S^T = K_tile * Q^T over staged tiles
  #pragma unroll
  for (int j=0; j<24; ++j){
    if (j < NT){
      __syncthreads();                               // tile j staged & ready
      if (j+1 < NT) stageK(Kn, &SB[((j+1)&1)*4096], KTLO+j+1, wid, l);
      const u16* kbuf = &SB[(j&1)*4096];
      #pragma unroll
      for (int ks=0; ks<8; ++ks){
        int boff = (ks*64 + lg*16) ^ ((lr&7)<<4);
        bfrag kf = ldb(kbuf + lr*256 + (boff>>1));
        acc[j] = MFMA16(kf, qa[ks], acc[j]);
      }
    }
  }

  // phase 2: in-register softmax (row q = q0w+lr across lg via shfl 16/32)
  int q = q0w + lr;
  float m = -1e30f;
  #pragma unroll
  for (int j=0;j<24;++j){
    if (j < NT){
      int colb = (KTLO+j)*16 + lg*4;
      #pragma unroll
      for (int r=0;r<4;++r){
        int d = q - (colb + r);
        bool v = (d < 133) && (d > -133);
        m = v ? fmaxf(m, acc[j][r]) : m;
      }
    }
  }
  m = fmaxf(m, __shfl_xor(m, 16, 64));
  m = fmaxf(m, __shfl_xor(m, 32, 64));
  float sum = 0.f;
  #pragma unroll
  for (int j=0;j<24;++j){
    if (j < NT){
      int colb = (KTLO+j)*16 + lg*4;
      #pragma unroll
      for (int r=0;r<4;++r){
        int d = q - (colb + r);
        bool v = (d < 133) && (d > -133);
        float e = v ? __expf(acc[j][r] - m) : 0.f;
        acc[j][r] = e; sum += e;
      }
    }
  }
  sum += __shfl_xor(sum, 16, 64);
  sum += __shfl_xor(sum, 32, 64);
  float rinv = 1.f / sum;

  char* PTw = (char*)&PT[wid][0][0];
  #pragma unroll
  for (int j=0;j<24;++j){
    if (j < NT){
      u16x4 pv;
      #pragma unroll
      for (int r=0;r<4;++r) pv[r] = f2bf(acc[j][r]*rinv);
      int boff = (j*32 + lg*8) ^ ((lr&7)<<4);
      *reinterpret_cast<u16x4*>(PTw + lr*768 + boff) = pv;
    }
  }

  // phase 3: O = P * Vpre (staged V chunks), folded-BN epilogue
  int nksp = NT >> 1;
  __syncthreads();                                   // K staging done; SB free for V
  stageV(Vn, &SB[0], KTLO*16, wid, l);
  ffrag o[16];
  #pragma unroll
  for (int i=0;i<16;++i) o[i] = fz;
  for (int ksp=0; ksp<nksp; ++ksp){
    __syncthreads();                                 // chunk ksp staged & ready
    if (ksp+1 < nksp) stageV(Vn, &SB[((ksp+1)&1)*8192], KTLO*16 + (ksp+1)*32, wid, l);
    bfrag pa = *reinterpret_cast<const bfrag*>(PTw + lr*768 + (((ksp*64 + lg*16) ^ ((lr&7)<<4))));
    const u16* vbuf = &SB[(ksp&1)*8192];
    #pragma unroll
    for (int ct=0; ct<16; ++ct){
      bfrag vf = ldb(vbuf + (ct*16 + lr)*32 + lg*8);
      o[ct] = MFMA16(pa, vf, o[ct]);
    }
  }
  #pragma unroll
  for (int ct=0; ct<16; ++ct){
    int c = ct*16 + lr;
    float av = aV[c], bv = bV[c];
    #pragma unroll
    for (int r=0;r<4;++r)
      O[((size_t)(n*512 + q0w + lg*4 + r))*256 + c] = f2bf(av*o[ct][r] + bv);
  }
}

// ---------- u BN stats, two-stage; fused streams ----------
__global__ __launch_bounds__(256) void k_ustat1(const u16* __restrict__ u1, const u16* __restrict__ u2,
                                                float* __restrict__ psum, float* __restrict__ psq){
  int s = blockIdx.y;
  const u16* u = s ? u2 : u1;
  float* ps = psum + (size_t)s*262144;
  float* pq = psq  + (size_t)s*262144;
  int bi = blockIdx.x, t = threadIdx.x;
  const u16* base = u + (size_t)bi*16384 + t;        // 64 rows x 256 c
  float sm=0.f, sq=0.f;
  #pragma unroll 4
  for (int r=0;r<64;++r){ float v = bf2f(base[r*256]); sm+=v; sq+=v*v; }
  ps[t*1024 + bi] = sm; pq[t*1024 + bi] = sq;
}
__global__ __launch_bounds__(256) void k_ustat2(const float* __restrict__ psum, const float* __restrict__ psq,
                                                const float* __restrict__ g, const float* __restrict__ be,
                                                float* __restrict__ aWall, float* __restrict__ bWall){
  int s = blockIdx.y, c = blockIdx.x, t = threadIdx.x;
  const float* ps = psum + (size_t)s*262144;
  const float* pq = psq  + (size_t)s*262144;
  float sm=0.f, sq=0.f;
  #pragma unroll
  for (int j=0;j<4;++j){ sm += ps[(size_t)c*1024 + t + j*256]; sq += pq[(size_t)c*1024 + t + j*256]; }
  __shared__ float rs[256], rq[256];
  rs[t]=sm; rq[t]=sq; __syncthreads();
  for (int st=128; st>0; st>>=1){ if (t<st){ rs[t]+=rs[t+st]; rq[t]+=rq[t+st]; } __syncthreads(); }
  if (t==0){
    float mean = rs[0]*(1.f/65536.f);
    float var  = rq[0]*(1.f/65536.f) - mean*mean;
    float aa = g[c]*rsqrtf(var + 1e-5f);
    aWall[s*256+c]=aa; bWall[s*256+c]=be[c]-aa*mean;
  }
}

// ---------- final: z = aW*u + bW + x (transpose back); fused streams ----------
__global__ __launch_bounds__(256) void k_final(const u16* __restrict__ u1, const u16* __restrict__ u2,
                                               const float* __restrict__ x1, const float* __restrict__ x2,
                                               const float* __restrict__ aWall, const float* __restrict__ bWall,
                                               float* __restrict__ z){
  int s = blockIdx.z;
  const u16* u = s ? u2 : u1;
  const float* x = s ? x2 : x1;
  const float* aW = aWall + s*256;
  const float* bW = bWall + s*256;
  float* zb = z + (size_t)s*16777216;
  __shared__ float T[64][65];
  int t = threadIdx.x;
  int p0 = blockIdx.x*64, c0 = blockIdx.y*64;
  int b = p0>>15, q0 = p0&32767;
  #pragma unroll
  for (int it=0; it<4; ++it){
    int pi = it*16 + (t>>4);
    int cj = (t&15)*4;
    u16x4 v; __builtin_memcpy(&v, u + (size_t)(p0+pi)*256 + c0 + cj, 8);
    #pragma unroll
    for (int j=0;j<4;++j) T[pi][cj+j] = bf2f(v[j]);
  }
  __syncthreads();
  #pragma unroll
  for (int it=0; it<16; ++it){
    int cc = it*4 + (t>>6);
    int qi = t&63;
    size_t addr = ((size_t)(b*256 + c0 + cc))*32768 + q0 + qi;
    zb[addr] = aW[c0+cc]*T[qi][cc] + bW[c0+cc] + x[addr];
  }
}

extern "C" void kernel_launch(void* const* d_in, const int* in_sizes, int n_in,
                              void* d_out, int out_size, void* d_ws, size_t ws_size,
                              hipStream_t stream) {
  const float* x1  = (const float*)d_in[0];
  const float* x2  = (const float*)d_in[1];
  const float* Qw  = (const float*)d_in[2];
  const float* Qb  = (const float*)d_in[3];
  const float* Kw  = (const float*)d_in[4];
  const float* Kb  = (const float*)d_in[5];
  const float* Vw  = (const float*)d_in[6];
  const float* Vb  = (const float*)d_in[7];
  const float* Vg  = (const float*)d_in[8];
  const float* Vbe = (const float*)d_in[9];
  const float* Ww  = (const float*)d_in[10];
  const float* Wb  = (const float*)d_in[11];
  const float* Wg  = (const float*)d_in[12];
  const float* Wbe = (const float*)d_in[13];

  char* ws = (char*)d_ws;
  const size_t S = 33554432;                  // one (65536 x 256) bf16 slot = 32 MB
  u16* xr1 = (u16*)(ws + 0*S);                // later reused as O1
  u16* xr2 = (u16*)(ws + 1*S);                // later reused as O2
  u16* Q1  = (u16*)(ws + 2*S);                // later reused as u1
  u16* K1  = (u16*)(ws + 3*S);                // later reused as u2
  u16* Q2  = (u16*)(ws + 4*S);
  u16* K2  = (u16*)(ws + 5*S);
  u16* wb  = (u16*)(ws + 6*S);                // 4 x 65536 bf16 = 512KB
  float* vec = (float*)(ws + 6*S + 524288);
  float* aVall = vec;                         // [2][256]
  float* bVall = vec + 512;
  float* aWall = vec + 1024;
  float* bWall = vec + 1536;
  float* vps   = vec + 2048;                  // [2][2048]
  float* vpq   = vps + 4096;                  // [2][2048]

  u16* Vt1 = (u16*)d_out;                     // d_out scratch (dead before z writes)
  u16* Vt2 = (u16*)((char*)d_out + S);
  float* upsum = (float*)((char*)d_out + 2*S); // [2][262144] (dead before z writes)
  float* upsq  = upsum + 524288;
  u16* O1 = xr1; u16* O2 = xr2;
  u16* u1 = Q1;  u16* u2 = K1;
  float* z = (float*)d_out;

  dim3 gt(1024, 4, 2);
  dim3 gq(1024, 1, 2);
  dim3 gv(256, 8, 2);
  dim3 gu1(1024, 2);
  dim3 gu2(256, 2);

  k_wcvt<<<256, 256, 0, stream>>>(Qw, Kw, Vw, Ww, wb);
  k_xpose<<<gt, 256, 0, stream>>>(x1, x2, xr1, xr2);
  k_qkv<<<gq, 256, 0, stream>>>(xr1, xr2, wb, Qb, Kb, Vb, Q1, K1, Vt1, Q2, K2, Vt2);
  k_vstat1<<<gv, 256, 0, stream>>>(Vt1, Vt2, vps, vpq);
  k_vstat2<<<2, 256, 0, stream>>>(vps, vpq, Vg, Vbe, aVall, bVall);
  k_attn<<<2048, 256, 0, stream>>>(Q1, K2, Vt2, Q2, K1, Vt1, aVall, bVall, O1, O2);
  k_conv1<<<gq, 256, 0, stream>>>(O1, O2, wb + 196608, Wb, u1, u2);
  k_ustat1<<<gu1, 256, 0, stream>>>(u1, u2, upsum, upsq);
  k_ustat2<<<gu2, 256, 0, stream>>>(upsum, upsq, Wg, Wbe, aWall, bWall);
  k_final<<<gt, 256, 0, stream>>>(u1, u2, x1, x2, aWall, bWall, z);
}

// Round 4
// 428.741 us; speedup vs baseline: 2.1172x; 1.2965x over previous
//
#include <hip/hip_runtime.h>

typedef unsigned short u16;
typedef short bfrag __attribute__((ext_vector_type(8)));   // 8 bf16 = one MFMA A/B frag
typedef float ffrag __attribute__((ext_vector_type(4)));   // MFMA C/D frag
typedef u16 u16x4 __attribute__((ext_vector_type(4)));

#define MFMA16(a,b,c) __builtin_amdgcn_mfma_f32_16x16x32_bf16((a),(b),(c),0,0,0)

// B=2, C=256, H=64, W=512 ; PIX=65536 ; NROW=B*H=128 ; max_w=int(512*0.26)=133 -> |i-j|<=132

__device__ __forceinline__ u16 f2bf(float f){
  union { float f; unsigned int i; } cv; cv.f = f;
  unsigned int x = cv.i;
  return (u16)((x + 0x7fffu + ((x >> 16) & 1u)) >> 16);  // RNE
}
__device__ __forceinline__ float bf2f(u16 u){
  union { unsigned int i; float f; } cv;
  cv.i = ((unsigned int)u) << 16;
  return cv.f;
}
__device__ __forceinline__ bfrag ldb(const u16* p){
  bfrag v; __builtin_memcpy(&v, p, 16); return v;
}
__device__ __forceinline__ void gload_lds16(const u16* g, u16* l){
  __builtin_amdgcn_global_load_lds(
      (const __attribute__((address_space(1))) unsigned int*)g,
      (__attribute__((address_space(3))) unsigned int*)l, 16, 0, 0);
}

// ---------- weights fp32 -> bf16 ----------
__global__ __launch_bounds__(256) void k_wcvt(const float* __restrict__ qw, const float* __restrict__ kw,
                                              const float* __restrict__ vw, const float* __restrict__ ww,
                                              u16* __restrict__ out){
  int t = blockIdx.x*256 + threadIdx.x;
  out[t]        = f2bf(qw[t]);
  out[t+65536]  = f2bf(kw[t]);
  out[t+131072] = f2bf(vw[t]);
  out[t+196608] = f2bf(ww[t]);
}

// ---------- x (B,C,H,W) fp32 -> xr (p, c) bf16 ; fused both streams via z ----------
__global__ __launch_bounds__(256) void k_xpose(const float* __restrict__ x1, const float* __restrict__ x2,
                                               u16* __restrict__ xr1, u16* __restrict__ xr2){
  const float* x = blockIdx.z ? x2 : x1;
  u16* xr = blockIdx.z ? xr2 : xr1;
  __shared__ float T[64][65];
  int t = threadIdx.x;
  int p0 = blockIdx.x*64, c0 = blockIdx.y*64;
  int b = p0 >> 15, q0 = p0 & 32767;
  #pragma unroll
  for (int it=0; it<4; ++it){
    int cc = it*16 + (t>>4);
    int pi = (t&15)*4;
    ffrag v; __builtin_memcpy(&v, x + ((size_t)(b*256 + c0 + cc))*32768 + q0 + pi, 16);
    T[cc][pi+0]=v[0]; T[cc][pi+1]=v[1]; T[cc][pi+2]=v[2]; T[cc][pi+3]=v[3];
  }
  __syncthreads();
  int pi = t>>2, cj0 = (t&3)*16;
  u16 tmp[16];
  #pragma unroll
  for (int j=0;j<16;++j) tmp[j] = f2bf(T[cj0+j][pi]);
  __builtin_memcpy(xr + (size_t)(p0+pi)*256 + c0 + cj0, tmp, 32);
}

// ---------- GEMM tile staging: 128 rows x 64 cols bf16 (16KB), XOR-swizzled ----------
__device__ __forceinline__ void stage_tile(const u16* __restrict__ src, int row0, int k0,
                                           u16* lds, int wid, int l){
  #pragma unroll
  for (int rr=0; rr<4; ++rr){
    int off = rr*4096 + wid*1024 + l*16;        // byte offset in 16KB tile
    int row = off>>7, inb = off&127;
    int srcb = inb ^ ((row&7)<<4);              // pre-swizzled source (rule 21)
    gload_lds16(src + (size_t)(row0+row)*256 + k0 + (srcb>>1),
                lds + ((rr*4096 + wid*1024)>>1));
  }
}

// ---------- fused QKV conv as tiled GEMM: 128x128 tile, BK=64 dbuf, V transposed ----------
__global__ __launch_bounds__(256, 2) void k_qkv(const u16* __restrict__ xr1, const u16* __restrict__ xr2,
    const u16* __restrict__ wb,
    const float* __restrict__ qb, const float* __restrict__ kb, const float* __restrict__ vb,
    u16* __restrict__ Q1, u16* __restrict__ K1, u16* __restrict__ V1,
    u16* __restrict__ Q2, u16* __restrict__ K2, u16* __restrict__ V2){
  __shared__ __align__(16) u16 As[2][8192];
  __shared__ __align__(16) u16 Bs[2][8192];
  int z = blockIdx.z, s = z/3, wgt = z - s*3;
  const u16* A = s ? xr2 : xr1;
  const u16* W = wb + wgt*65536;
  const float* bias = (wgt==0)? qb : (wgt==1)? kb : vb;

  int t = threadIdx.x, wid = t>>6, l = t&63, lr = l&15, lg = l>>4;
  int p0 = blockIdx.x*128, o0 = blockIdx.y*128;
  int wr = (wid>>1)*64, wc = (wid&1)*64;
  int swz = (lr&7)<<4;

  stage_tile(A, p0, 0, As[0], wid, l);
  stage_tile(W, o0, 0, Bs[0], wid, l);

  const ffrag fz = {0.f,0.f,0.f,0.f};
  ffrag acc[4][4];
  #pragma unroll
  for (int i=0;i<4;++i){ acc[i][0]=fz; acc[i][1]=fz; acc[i][2]=fz; acc[i][3]=fz; }

  #pragma unroll
  for (int ks=0; ks<4; ++ks){
    __syncthreads();
    if (ks < 3){
      stage_tile(A, p0, (ks+1)*64, As[(ks+1)&1], wid, l);
      stage_tile(W, o0, (ks+1)*64, Bs[(ks+1)&1], wid, l);
    }
    const u16* as = As[ks&1];
    const u16* bs = Bs[ks&1];
    #pragma unroll
    for (int kc=0; kc<2; ++kc){
      int colb = (kc*64 + lg*16) ^ swz;
      bfrag af[4], bfm[4];
      #pragma unroll
      for (int mt=0; mt<4; ++mt)
        af[mt] = ldb(as + (((wr + mt*16 + lr)*128 + colb)>>1));
      #pragma unroll
      for (int nt=0; nt<4; ++nt)
        bfm[nt] = ldb(bs + (((wc + nt*16 + lr)*128 + colb)>>1));
      #pragma unroll
      for (int mt=0; mt<4; ++mt)
        #pragma unroll
        for (int nt=0; nt<4; ++nt)
          acc[mt][nt] = MFMA16(af[mt], bfm[nt], acc[mt][nt]);
    }
  }

  u16* Qo = s ? Q2 : Q1;
  u16* Ko = s ? K2 : K1;
  u16* Vt = s ? V2 : V1;
  #pragma unroll
  for (int nt=0; nt<4; ++nt){
    int oo = o0 + wc + nt*16 + lr;
    float bsc = bias[oo];
    #pragma unroll
    for (int mt=0; mt<4; ++mt){
      int pr = p0 + wr + mt*16 + lg*4;
      if (wgt == 2){
        int n = pr >> 9, w0 = pr & 511;
        u16x4 vv;
        #pragma unroll
        for (int r=0;r<4;++r) vv[r] = f2bf(acc[mt][nt][r] + bsc);
        *reinterpret_cast<u16x4*>(Vt + ((size_t)(n*256 + oo))*512 + w0) = vv;
      } else {
        u16* op = (wgt==0)? Qo : Ko;
        #pragma unroll
        for (int r=0;r<4;++r)
          op[(size_t)(pr + r)*256 + oo] = f2bf(acc[mt][nt][r] + bsc);
      }
    }
  }
}

// ---------- W conv as tiled GEMM (same structure, plain epilogue) ----------
__global__ __launch_bounds__(256, 2) void k_conv1(const u16* __restrict__ in1, const u16* __restrict__ in2,
    const u16* __restrict__ wp, const float* __restrict__ bias,
    u16* __restrict__ o1, u16* __restrict__ o2){
  __shared__ __align__(16) u16 As[2][8192];
  __shared__ __align__(16) u16 Bs[2][8192];
  int s = blockIdx.z;
  const u16* A = s ? in2 : in1;
  u16* out = s ? o2 : o1;

  int t = threadIdx.x, wid = t>>6, l = t&63, lr = l&15, lg = l>>4;
  int p0 = blockIdx.x*128, o0 = blockIdx.y*128;
  int wr = (wid>>1)*64, wc = (wid&1)*64;
  int swz = (lr&7)<<4;

  stage_tile(A, p0, 0, As[0], wid, l);
  stage_tile(wp, o0, 0, Bs[0], wid, l);

  const ffrag fz = {0.f,0.f,0.f,0.f};
  ffrag acc[4][4];
  #pragma unroll
  for (int i=0;i<4;++i){ acc[i][0]=fz; acc[i][1]=fz; acc[i][2]=fz; acc[i][3]=fz; }

  #pragma unroll
  for (int ks=0; ks<4; ++ks){
    __syncthreads();
    if (ks < 3){
      stage_tile(A, p0, (ks+1)*64, As[(ks+1)&1], wid, l);
      stage_tile(wp, o0, (ks+1)*64, Bs[(ks+1)&1], wid, l);
    }
    const u16* as = As[ks&1];
    const u16* bs = Bs[ks&1];
    #pragma unroll
    for (int kc=0; kc<2; ++kc){
      int colb = (kc*64 + lg*16) ^ swz;
      bfrag af[4], bfm[4];
      #pragma unroll
      for (int mt=0; mt<4; ++mt)
        af[mt] = ldb(as + (((wr + mt*16 + lr)*128 + colb)>>1));
      #pragma unroll
      for (int nt=0; nt<4; ++nt)
        bfm[nt] = ldb(bs + (((wc + nt*16 + lr)*128 + colb)>>1));
      #pragma unroll
      for (int mt=0; mt<4; ++mt)
        #pragma unroll
        for (int nt=0; nt<4; ++nt)
          acc[mt][nt] = MFMA16(af[mt], bfm[nt], acc[mt][nt]);
    }
  }

  #pragma unroll
  for (int nt=0; nt<4; ++nt){
    int oo = o0 + wc + nt*16 + lr;
    float bsc = bias[oo];
    #pragma unroll
    for (int mt=0; mt<4; ++mt){
      int pr = p0 + wr + mt*16 + lg*4;
      #pragma unroll
      for (int r=0;r<4;++r)
        out[(size_t)(pr + r)*256 + oo] = f2bf(acc[mt][nt][r] + bsc);
    }
  }
}

// ---------- V BN stats, two-stage; fused streams ----------
__global__ __launch_bounds__(256) void k_vstat1(const u16* __restrict__ V1, const u16* __restrict__ V2,
                                                float* __restrict__ ps, float* __restrict__ pq){
  int s = blockIdx.z;
  const u16* Vt = s ? V2 : V1;
  int c = blockIdx.x, ch = blockIdx.y, t = threadIdx.x;
  float sm=0.f, sq=0.f;
  for (int nn=0; nn<16; ++nn){
    const u16* row = Vt + ((size_t)((ch*16+nn)*256 + c))*512 + t;
    float v = bf2f(row[0]);   sm+=v; sq+=v*v;
    v = bf2f(row[256]);       sm+=v; sq+=v*v;
  }
  __shared__ float rs[256], rq[256];
  rs[t]=sm; rq[t]=sq; __syncthreads();
  for (int st=128; st>0; st>>=1){ if (t<st){ rs[t]+=rs[t+st]; rq[t]+=rq[t+st]; } __syncthreads(); }
  if (t==0){ ps[s*2048 + c*8+ch]=rs[0]; pq[s*2048 + c*8+ch]=rq[0]; }
}
__global__ __launch_bounds__(256) void k_vstat2(const float* __restrict__ ps, const float* __restrict__ pq,
                                                const float* __restrict__ g, const float* __restrict__ be,
                                                float* __restrict__ aVall, float* __restrict__ bVall){
  int s = blockIdx.x, c = threadIdx.x;
  float sm=0.f, sq=0.f;
  #pragma unroll
  for (int ch=0; ch<8; ++ch){ sm += ps[s*2048 + c*8+ch]; sq += pq[s*2048 + c*8+ch]; }
  float mean = sm*(1.f/65536.f);
  float var  = sq*(1.f/65536.f) - mean*mean;
  float aa = g[c]*rsqrtf(var + 1e-5f);
  aVall[s*256+c]=aa; bVall[s*256+c]=be[c]-aa*mean;
}

// ---------- staging helpers for k_attn ----------
__device__ __forceinline__ void stageK(const u16* Kn, u16* kb, int kt, int wid, int l){
  #pragma unroll
  for (int c2=0; c2<2; ++c2){
    int off = wid*2048 + c2*1024 + l*16;            // byte offset in 8KB tile
    int row = off>>9, inb = off&511;
    int src = inb ^ ((row&7)<<4);                   // pre-swizzled source
    gload_lds16(Kn + (size_t)(kt*16+row)*256 + (src>>1), kb + wid*1024 + c2*512);
  }
}
__device__ __forceinline__ void stageV(const u16* Vn, u16* vb, int k0, int wid, int l){
  #pragma unroll
  for (int c4=0; c4<4; ++c4){
    int off = wid*4096 + c4*1024 + l*16;            // byte offset in 16KB tile
    int crow = off>>6, inb = off&63;
    gload_lds16(Vn + (size_t)crow*512 + k0 + (inb>>1), vb + wid*2048 + c4*512);
  }
}

// ---------- banded attention v3: block-uniform band, LDS-staged K/V, double-buffered ----------
__global__ __launch_bounds__(256, 2) void k_attn(
    const u16* __restrict__ Q1, const u16* __restrict__ K2, const u16* __restrict__ V2,
    const u16* __restrict__ Q2, const u16* __restrict__ K1, const u16* __restrict__ V1,
    const float* __restrict__ aVall, const float* __restrict__ bVall,
    u16* __restrict__ O1, u16* __restrict__ O2){
  __shared__ __align__(16) u16 PT[4][16][384];      // 48KB: per-wave P rows (768B stride, XOR-swz)
  __shared__ __align__(16) u16 SB[16384];           // 32KB: K dbuf (2x8KB) / V dbuf (2x16KB), phase-shared
  int t = threadIdx.x, wid = t>>6, l = t&63, lr = l&15, lg = l>>4;
  int id = blockIdx.x;
  int s = id >> 10;                                  // stream high-bit: XCD phases see one stream
  int r0 = id & 1023;
  int xcd = r0 & 7, s5 = r0 >> 3;
  int qb = s5 & 7, n = (xcd<<4) | (s5>>3);
  const u16* Q = s ? Q2 : Q1;
  const u16* K = s ? K1 : K2;
  const u16* V = s ? V1 : V2;
  const float* aV = aVall + (s ? 0 : 256);           // y1 uses V2's stats
  const float* bV = bVall + (s ? 0 : 256);
  u16* O = s ? O2 : O1;

  int q0 = qb*64, q0w = q0 + wid*16;
  int lo = q0 - 132; if (lo < 0) lo = 0;
  int hi = q0 + 195; if (hi > 511) hi = 511;
  int KTLO = (lo>>4) & ~1;                           // even
  int KTHI = (hi>>4) | 1;                            // odd
  int NT = KTHI - KTLO + 1;                          // even, <= 24

  const u16* Kn = K + (size_t)n*131072;
  const u16* Vn = V + (size_t)n*131072;

  stageK(Kn, &SB[0], KTLO, wid, l);                  // prologue stage tile 0

  // Q frags (16 rows x 256 c)
  bfrag qa[8];
  const u16* Qrow = Q + ((size_t)(n*512 + q0w + lr))*256 + lg*8;
  #pragma unroll
  for (int ks=0; ks<8; ++ks) qa[ks] = ldb(Qrow + ks*32);

  const ffrag fz = {0.f,0.f,0.f,0.f};
  ffrag acc[24];
  #pragma unroll
  for (int i=0;i<24;++i) acc[i] = fz;

  // phase 1: S^T = K_tile * Q^T over staged tiles
  #pragma unroll
  for (int j=0; j<24; ++j){
    if (j < NT){
      __syncthreads();                               // tile j staged & ready
      if (j+1 < NT) stageK(Kn, &SB[((j+1)&1)*4096], KTLO+j+1, wid, l);
      const u16* kbuf = &SB[(j&1)*4096];
      #pragma unroll
      for (int ks=0; ks<8; ++ks){
        int boff = (ks*64 + lg*16) ^ ((lr&7)<<4);
        bfrag kf = ldb(kbuf + lr*256 + (boff>>1));
        acc[j] = MFMA16(kf, qa[ks], acc[j]);
      }
    }
  }

  // phase 2: in-register softmax (row q = q0w+lr across lg via shfl 16/32)
  int q = q0w + lr;
  float m = -1e30f;
  #pragma unroll
  for (int j=0;j<24;++j){
    if (j < NT){
      int colb = (KTLO+j)*16 + lg*4;
      #pragma unroll
      for (int r=0;r<4;++r){
        int d = q - (colb + r);
        bool v = (d < 133) && (d > -133);
        m = v ? fmaxf(m, acc[j][r]) : m;
      }
    }
  }
  m = fmaxf(m, __shfl_xor(m, 16, 64));
  m = fmaxf(m, __shfl_xor(m, 32, 64));
  float sum = 0.f;
  #pragma unroll
  for (int j=0;j<24;++j){
    if (j < NT){
      int colb = (KTLO+j)*16 + lg*4;
      #pragma unroll
      for (int r=0;r<4;++r){
        int d = q - (colb + r);
        bool v = (d < 133) && (d > -133);
        float e = v ? __expf(acc[j][r] - m) : 0.f;
        acc[j][r] = e; sum += e;
      }
    }
  }
  sum += __shfl_xor(sum, 16, 64);
  sum += __shfl_xor(sum, 32, 64);
  float rinv = 1.f / sum;

  char* PTw = (char*)&PT[wid][0][0];
  #pragma unroll
  for (int j=0;j<24;++j){
    if (j < NT){
      u16x4 pv;
      #pragma unroll
      for (int r=0;r<4;++r) pv[r] = f2bf(acc[j][r]*rinv);
      int boff = (j*32 + lg*8) ^ ((lr&7)<<4);
      *reinterpret_cast<u16x4*>(PTw + lr*768 + boff) = pv;
    }
  }

  // phase 3: O = P * Vpre (staged V chunks), folded-BN epilogue
  int nksp = NT >> 1;
  __syncthreads();                                   // K staging done; SB free for V
  stageV(Vn, &SB[0], KTLO*16, wid, l);
  ffrag o[16];
  #pragma unroll
  for (int i=0;i<16;++i) o[i] = fz;
  for (int ksp=0; ksp<nksp; ++ksp){
    __syncthreads();                                 // chunk ksp staged & ready
    if (ksp+1 < nksp) stageV(Vn, &SB[((ksp+1)&1)*8192], KTLO*16 + (ksp+1)*32, wid, l);
    bfrag pa = *reinterpret_cast<const bfrag*>(PTw + lr*768 + (((ksp*64 + lg*16) ^ ((lr&7)<<4))));
    const u16* vbuf = &SB[(ksp&1)*8192];
    #pragma unroll
    for (int ct=0; ct<16; ++ct){
      bfrag vf = ldb(vbuf + (ct*16 + lr)*32 + lg*8);
      o[ct] = MFMA16(pa, vf, o[ct]);
    }
  }
  #pragma unroll
  for (int ct=0; ct<16; ++ct){
    int c = ct*16 + lr;
    float av = aV[c], bv = bV[c];
    #pragma unroll
    for (int r=0;r<4;++r)
      O[((size_t)(n*512 + q0w + lg*4 + r))*256 + c] = f2bf(av*o[ct][r] + bv);
  }
}

// ---------- u BN stats, two-stage; fused streams ----------
__global__ __launch_bounds__(256) void k_ustat1(const u16* __restrict__ u1, const u16* __restrict__ u2,
                                                float* __restrict__ psum, float* __restrict__ psq){
  int s = blockIdx.y;
  const u16* u = s ? u2 : u1;
  float* ps = psum + (size_t)s*262144;
  float* pq = psq  + (size_t)s*262144;
  int bi = blockIdx.x, t = threadIdx.x;
  const u16* base = u + (size_t)bi*16384 + t;        // 64 rows x 256 c
  float sm=0.f, sq=0.f;
  #pragma unroll 4
  for (int r=0;r<64;++r){ float v = bf2f(base[r*256]); sm+=v; sq+=v*v; }
  ps[t*1024 + bi] = sm; pq[t*1024 + bi] = sq;
}
__global__ __launch_bounds__(256) void k_ustat2(const float* __restrict__ psum, const float* __restrict__ psq,
                                                const float* __restrict__ g, const float* __restrict__ be,
                                                float* __restrict__ aWall, float* __restrict__ bWall){
  int s = blockIdx.y, c = blockIdx.x, t = threadIdx.x;
  const float* ps = psum + (size_t)s*262144;
  const float* pq = psq  + (size_t)s*262144;
  float sm=0.f, sq=0.f;
  #pragma unroll
  for (int j=0;j<4;++j){ sm += ps[(size_t)c*1024 + t + j*256]; sq += pq[(size_t)c*1024 + t + j*256]; }
  __shared__ float rs[256], rq[256];
  rs[t]=sm; rq[t]=sq; __syncthreads();
  for (int st=128; st>0; st>>=1){ if (t<st){ rs[t]+=rs[t+st]; rq[t]+=rq[t+st]; } __syncthreads(); }
  if (t==0){
    float mean = rs[0]*(1.f/65536.f);
    float var  = rq[0]*(1.f/65536.f) - mean*mean;
    float aa = g[c]*rsqrtf(var + 1e-5f);
    aWall[s*256+c]=aa; bWall[s*256+c]=be[c]-aa*mean;
  }
}

// ---------- final: z = aW*u + bW + x (transpose back); fused streams ----------
__global__ __launch_bounds__(256) void k_final(const u16* __restrict__ u1, const u16* __restrict__ u2,
                                               const float* __restrict__ x1, const float* __restrict__ x2,
                                               const float* __restrict__ aWall, const float* __restrict__ bWall,
                                               float* __restrict__ z){
  int s = blockIdx.z;
  const u16* u = s ? u2 : u1;
  const float* x = s ? x2 : x1;
  const float* aW = aWall + s*256;
  const float* bW = bWall + s*256;
  float* zb = z + (size_t)s*16777216;
  __shared__ float T[64][65];
  int t = threadIdx.x;
  int p0 = blockIdx.x*64, c0 = blockIdx.y*64;
  int b = p0>>15, q0 = p0&32767;
  #pragma unroll
  for (int it=0; it<4; ++it){
    int pi = it*16 + (t>>4);
    int cj = (t&15)*4;
    u16x4 v; __builtin_memcpy(&v, u + (size_t)(p0+pi)*256 + c0 + cj, 8);
    #pragma unroll
    for (int j=0;j<4;++j) T[pi][cj+j] = bf2f(v[j]);
  }
  __syncthreads();
  #pragma unroll
  for (int it=0; it<16; ++it){
    int cc = it*4 + (t>>6);
    int qi = t&63;
    size_t addr = ((size_t)(b*256 + c0 + cc))*32768 + q0 + qi;
    zb[addr] = aW[c0+cc]*T[qi][cc] + bW[c0+cc] + x[addr];
  }
}

extern "C" void kernel_launch(void* const* d_in, const int* in_sizes, int n_in,
                              void* d_out, int out_size, void* d_ws, size_t ws_size,
                              hipStream_t stream) {
  const float* x1  = (const float*)d_in[0];
  const float* x2  = (const float*)d_in[1];
  const float* Qw  = (const float*)d_in[2];
  const float* Qb  = (const float*)d_in[3];
  const float* Kw  = (const float*)d_in[4];
  const float* Kb  = (const float*)d_in[5];
  const float* Vw  = (const float*)d_in[6];
  const float* Vb  = (const float*)d_in[7];
  const float* Vg  = (const float*)d_in[8];
  const float* Vbe = (const float*)d_in[9];
  const float* Ww  = (const float*)d_in[10];
  const float* Wb  = (const float*)d_in[11];
  const float* Wg  = (const float*)d_in[12];
  const float* Wbe = (const float*)d_in[13];

  char* ws = (char*)d_ws;
  const size_t S = 33554432;                  // one (65536 x 256) bf16 slot = 32 MB
  u16* xr1 = (u16*)(ws + 0*S);                // later reused as O1
  u16* xr2 = (u16*)(ws + 1*S);                // later reused as O2
  u16* Q1  = (u16*)(ws + 2*S);                // later reused as u1
  u16* K1  = (u16*)(ws + 3*S);                // later reused as u2
  u16* Q2  = (u16*)(ws + 4*S);
  u16* K2  = (u16*)(ws + 5*S);
  u16* wb  = (u16*)(ws + 6*S);                // 4 x 65536 bf16 = 512KB
  float* vec = (float*)(ws + 6*S + 524288);
  float* aVall = vec;                         // [2][256]
  float* bVall = vec + 512;
  float* aWall = vec + 1024;
  float* bWall = vec + 1536;
  float* vps   = vec + 2048;                  // [2][2048]
  float* vpq   = vps + 4096;                  // [2][2048]

  u16* Vt1 = (u16*)d_out;                     // d_out scratch (dead before z writes)
  u16* Vt2 = (u16*)((char*)d_out + S);
  float* upsum = (float*)((char*)d_out + 2*S); // [2][262144] (dead before z writes)
  float* upsq  = upsum + 524288;
  u16* O1 = xr1; u16* O2 = xr2;
  u16* u1 = Q1;  u16* u2 = K1;
  float* z = (float*)d_out;

  dim3 gt(1024, 4, 2);
  dim3 gg(512, 2, 6);
  dim3 gc(512, 2, 2);
  dim3 gv(256, 8, 2);
  dim3 gu1(1024, 2);
  dim3 gu2(256, 2);

  k_wcvt<<<256, 256, 0, stream>>>(Qw, Kw, Vw, Ww, wb);
  k_xpose<<<gt, 256, 0, stream>>>(x1, x2, xr1, xr2);
  k_qkv<<<gg, 256, 0, stream>>>(xr1, xr2, wb, Qb, Kb, Vb, Q1, K1, Vt1, Q2, K2, Vt2);
  k_vstat1<<<gv, 256, 0, stream>>>(Vt1, Vt2, vps, vpq);
  k_vstat2<<<2, 256, 0, stream>>>(vps, vpq, Vg, Vbe, aVall, bVall);
  k_attn<<<2048, 256, 0, stream>>>(Q1, K2, Vt2, Q2, K1, Vt1, aVall, bVall, O1, O2);
  k_conv1<<<gc, 256, 0, stream>>>(O1, O2, wb + 196608, Wb, u1, u2);
  k_ustat1<<<gu1, 256, 0, stream>>>(u1, u2, upsum, upsq);
  k_ustat2<<<gu2, 256, 0, stream>>>(upsum, upsq, Wg, Wbe, aWall, bWall);
  k_final<<<gt, 256, 0, stream>>>(u1, u2, x1, x2, aWall, bWall, z);
}

// Round 6
// 386.235 us; speedup vs baseline: 2.3502x; 1.1101x over previous
//
#include <hip/hip_runtime.h>

typedef unsigned short u16;
typedef short bfrag __attribute__((ext_vector_type(8)));   // 8 bf16 = one MFMA A/B frag
typedef float ffrag __attribute__((ext_vector_type(4)));   // MFMA C/D frag
typedef u16 u16x4 __attribute__((ext_vector_type(4)));

#define MFMA16(a,b,c) __builtin_amdgcn_mfma_f32_16x16x32_bf16((a),(b),(c),0,0,0)

#define WAITV(N) do { asm volatile("s_waitcnt vmcnt(" #N ")" ::: "memory"); \
                      __builtin_amdgcn_sched_barrier(0); } while(0)
#define RBAR()   do { __builtin_amdgcn_s_barrier(); \
                      __builtin_amdgcn_sched_barrier(0); } while(0)

// B=2, C=256, H=64, W=512 ; PIX=65536 ; NROW=B*H=128 ; max_w=int(512*0.26)=133 -> |i-j|<=132

__device__ __forceinline__ u16 f2bf(float f){
  union { float f; unsigned int i; } cv; cv.f = f;
  unsigned int x = cv.i;
  return (u16)((x + 0x7fffu + ((x >> 16) & 1u)) >> 16);  // RNE
}
__device__ __forceinline__ float bf2f(u16 u){
  union { unsigned int i; float f; } cv;
  cv.i = ((unsigned int)u) << 16;
  return cv.f;
}
__device__ __forceinline__ bfrag ldb(const u16* p){
  bfrag v; __builtin_memcpy(&v, p, 16); return v;
}
__device__ __forceinline__ void gload_lds16(const u16* g, u16* l){
  __builtin_amdgcn_global_load_lds(
      (const __attribute__((address_space(1))) unsigned int*)g,
      (__attribute__((address_space(3))) unsigned int*)l, 16, 0, 0);
}

// ---------- weights fp32 -> bf16 ----------
__global__ __launch_bounds__(256) void k_wcvt(const float* __restrict__ qw, const float* __restrict__ kw,
                                              const float* __restrict__ vw, const float* __restrict__ ww,
                                              u16* __restrict__ out){
  int t = blockIdx.x*256 + threadIdx.x;
  out[t]        = f2bf(qw[t]);
  out[t+65536]  = f2bf(kw[t]);
  out[t+131072] = f2bf(vw[t]);
  out[t+196608] = f2bf(ww[t]);
}

// ---------- x (B,C,H,W) fp32 -> xr (p, c) bf16 ; fused both streams via z ----------
__global__ __launch_bounds__(256) void k_xpose(const float* __restrict__ x1, const float* __restrict__ x2,
                                               u16* __restrict__ xr1, u16* __restrict__ xr2){
  const float* x = blockIdx.z ? x2 : x1;
  u16* xr = blockIdx.z ? xr2 : xr1;
  __shared__ float T[64][65];
  int t = threadIdx.x;
  int p0 = blockIdx.x*64, c0 = blockIdx.y*64;
  int b = p0 >> 15, q0 = p0 & 32767;
  #pragma unroll
  for (int it=0; it<4; ++it){
    int cc = it*16 + (t>>4);
    int pi = (t&15)*4;
    ffrag v; __builtin_memcpy(&v, x + ((size_t)(b*256 + c0 + cc))*32768 + q0 + pi, 16);
    T[cc][pi+0]=v[0]; T[cc][pi+1]=v[1]; T[cc][pi+2]=v[2]; T[cc][pi+3]=v[3];
  }
  __syncthreads();
  int pi = t>>2, cj0 = (t&3)*16;
  u16 tmp[16];
  #pragma unroll
  for (int j=0;j<16;++j) tmp[j] = f2bf(T[cj0+j][pi]);
  __builtin_memcpy(xr + (size_t)(p0+pi)*256 + c0 + cj0, tmp, 32);
}

// ---------- GEMM tile staging: 128 rows x 64 cols bf16 (16KB), XOR-swizzled ----------
__device__ __forceinline__ void stage_tile(const u16* __restrict__ src, int row0, int k0,
                                           u16* lds, int wid, int l){
  #pragma unroll
  for (int rr=0; rr<4; ++rr){
    int off = rr*4096 + wid*1024 + l*16;        // byte offset in 16KB tile
    int row = off>>7, inb = off&127;
    int srcb = inb ^ ((row&7)<<4);              // pre-swizzled source (rule 21)
    gload_lds16(src + (size_t)(row0+row)*256 + k0 + (srcb>>1),
                lds + ((rr*4096 + wid*1024)>>1));
  }
}

// ---------- fused QKV conv, XCD-chunked so all 12 variants of a p-tile co-locate ----------
__global__ __launch_bounds__(256, 2) void k_qkv(const u16* __restrict__ xr1, const u16* __restrict__ xr2,
    const u16* __restrict__ wb,
    const float* __restrict__ qb, const float* __restrict__ kb, const float* __restrict__ vb,
    u16* __restrict__ Q1, u16* __restrict__ K1, u16* __restrict__ V1,
    u16* __restrict__ Q2, u16* __restrict__ K2, u16* __restrict__ V2){
  __shared__ __align__(16) u16 As[2][8192];
  __shared__ __align__(16) u16 Bs[2][8192];
  int id = blockIdx.x;
  int xcd = id & 7, j = id >> 3;               // 768 per XCD
  int pl = j/12, v = j - pl*12;                // 64 p-tiles x 12 variants
  int ptile = xcd*64 + pl;
  int ot = v & 1, r = v >> 1;
  int wgt = r >> 1, s = r & 1;
  const u16* A = s ? xr2 : xr1;
  const u16* W = wb + wgt*65536;
  const float* bias = (wgt==0)? qb : (wgt==1)? kb : vb;

  int t = threadIdx.x, wid = t>>6, l = t&63, lr = l&15, lg = l>>4;
  int p0 = ptile*128, o0 = ot*128;
  int wr = (wid>>1)*64, wc = (wid&1)*64;
  int swz = (lr&7)<<4;

  stage_tile(A, p0, 0, As[0], wid, l);
  stage_tile(W, o0, 0, Bs[0], wid, l);

  const ffrag fz = {0.f,0.f,0.f,0.f};
  ffrag acc[4][4];
  #pragma unroll
  for (int i=0;i<4;++i){ acc[i][0]=fz; acc[i][1]=fz; acc[i][2]=fz; acc[i][3]=fz; }

  #pragma unroll
  for (int ks=0; ks<4; ++ks){
    __syncthreads();
    if (ks < 3){
      stage_tile(A, p0, (ks+1)*64, As[(ks+1)&1], wid, l);
      stage_tile(W, o0, (ks+1)*64, Bs[(ks+1)&1], wid, l);
    }
    const u16* as = As[ks&1];
    const u16* bs = Bs[ks&1];
    #pragma unroll
    for (int kc=0; kc<2; ++kc){
      int colb = (kc*64 + lg*16) ^ swz;
      bfrag af[4], bfm[4];
      #pragma unroll
      for (int mt=0; mt<4; ++mt)
        af[mt] = ldb(as + (((wr + mt*16 + lr)*128 + colb)>>1));
      #pragma unroll
      for (int nt=0; nt<4; ++nt)
        bfm[nt] = ldb(bs + (((wc + nt*16 + lr)*128 + colb)>>1));
      #pragma unroll
      for (int mt=0; mt<4; ++mt)
        #pragma unroll
        for (int nt=0; nt<4; ++nt)
          acc[mt][nt] = MFMA16(af[mt], bfm[nt], acc[mt][nt]);
    }
  }

  u16* Qo = s ? Q2 : Q1;
  u16* Ko = s ? K2 : K1;
  u16* Vt = s ? V2 : V1;
  #pragma unroll
  for (int nt=0; nt<4; ++nt){
    int oo = o0 + wc + nt*16 + lr;
    float bsc = bias[oo];
    #pragma unroll
    for (int mt=0; mt<4; ++mt){
      int pr = p0 + wr + mt*16 + lg*4;
      if (wgt == 2){
        int n = pr >> 9, w0 = pr & 511;
        u16x4 vv;
        #pragma unroll
        for (int rr=0;rr<4;++rr) vv[rr] = f2bf(acc[mt][nt][rr] + bsc);
        *reinterpret_cast<u16x4*>(Vt + ((size_t)(n*256 + oo))*512 + w0) = vv;
      } else {
        u16* op = (wgt==0)? Qo : Ko;
        #pragma unroll
        for (int rr=0;rr<4;++rr)
          op[(size_t)(pr + rr)*256 + oo] = f2bf(acc[mt][nt][rr] + bsc);
      }
    }
  }
}

// ---------- W conv + fused BN partial stats; XCD-chunked ----------
__global__ __launch_bounds__(256, 2) void k_conv1(const u16* __restrict__ in1, const u16* __restrict__ in2,
    const u16* __restrict__ wp, const float* __restrict__ bias,
    u16* __restrict__ o1, u16* __restrict__ o2,
    float* __restrict__ psum, float* __restrict__ psq){
  __shared__ __align__(16) u16 As[2][8192];
  __shared__ __align__(16) u16 Bs[2][8192];
  int id = blockIdx.x;
  int xcd = id & 7, j = id >> 3;               // 256 per XCD
  int pl = j>>2, v = j&3;
  int ptile = xcd*64 + pl;
  int ot = v & 1, s = v >> 1;
  const u16* A = s ? in2 : in1;
  u16* out = s ? o2 : o1;

  int t = threadIdx.x, wid = t>>6, l = t&63, lr = l&15, lg = l>>4;
  int p0 = ptile*128, o0 = ot*128;
  int wr = (wid>>1)*64, wc = (wid&1)*64;
  int swz = (lr&7)<<4;

  stage_tile(A, p0, 0, As[0], wid, l);
  stage_tile(wp, o0, 0, Bs[0], wid, l);

  const ffrag fz = {0.f,0.f,0.f,0.f};
  ffrag acc[4][4];
  #pragma unroll
  for (int i=0;i<4;++i){ acc[i][0]=fz; acc[i][1]=fz; acc[i][2]=fz; acc[i][3]=fz; }

  #pragma unroll
  for (int ks=0; ks<4; ++ks){
    __syncthreads();
    if (ks < 3){
      stage_tile(A, p0, (ks+1)*64, As[(ks+1)&1], wid, l);
      stage_tile(wp, o0, (ks+1)*64, Bs[(ks+1)&1], wid, l);
    }
    const u16* as = As[ks&1];
    const u16* bs = Bs[ks&1];
    #pragma unroll
    for (int kc=0; kc<2; ++kc){
      int colb = (kc*64 + lg*16) ^ swz;
      bfrag af[4], bfm[4];
      #pragma unroll
      for (int mt=0; mt<4; ++mt)
        af[mt] = ldb(as + (((wr + mt*16 + lr)*128 + colb)>>1));
      #pragma unroll
      for (int nt=0; nt<4; ++nt)
        bfm[nt] = ldb(bs + (((wc + nt*16 + lr)*128 + colb)>>1));
      #pragma unroll
      for (int mt=0; mt<4; ++mt)
        #pragma unroll
        for (int nt=0; nt<4; ++nt)
          acc[mt][nt] = MFMA16(af[mt], bfm[nt], acc[mt][nt]);
    }
  }

  float pv[4], qv[4];
  #pragma unroll
  for (int nt=0; nt<4; ++nt){ pv[nt]=0.f; qv[nt]=0.f; }
  #pragma unroll
  for (int nt=0; nt<4; ++nt){
    int oo = o0 + wc + nt*16 + lr;
    float bsc = bias[oo];
    #pragma unroll
    for (int mt=0; mt<4; ++mt){
      int pr = p0 + wr + mt*16 + lg*4;
      #pragma unroll
      for (int rr=0;rr<4;++rr){
        float val = acc[mt][nt][rr] + bsc;
        out[(size_t)(pr + rr)*256 + oo] = f2bf(val);
        pv[nt] += val; qv[nt] += val*val;
      }
    }
  }
  #pragma unroll
  for (int nt=0; nt<4; ++nt){
    float sv = pv[nt], sq = qv[nt];
    sv += __shfl_xor(sv,16,64); sv += __shfl_xor(sv,32,64);
    sq += __shfl_xor(sq,16,64); sq += __shfl_xor(sq,32,64);
    if (lg==0){
      int oo = o0 + wc + nt*16 + lr;
      int idx = ((s*256 + oo)<<10) + (ptile<<1) + (wr>>6);
      psum[idx] = sv; psq[idx] = sq;
    }
  }
}

// ---------- V BN stats, two-stage; fused streams ----------
__global__ __launch_bounds__(256) void k_vstat1(const u16* __restrict__ V1, const u16* __restrict__ V2,
                                                float* __restrict__ ps, float* __restrict__ pq){
  int s = blockIdx.z;
  const u16* Vt = s ? V2 : V1;
  int c = blockIdx.x, ch = blockIdx.y, t = threadIdx.x;
  float sm=0.f, sq=0.f;
  for (int nn=0; nn<16; ++nn){
    const u16* row = Vt + ((size_t)((ch*16+nn)*256 + c))*512 + t;
    float v = bf2f(row[0]);   sm+=v; sq+=v*v;
    v = bf2f(row[256]);       sm+=v; sq+=v*v;
  }
  __shared__ float rs[256], rq[256];
  rs[t]=sm; rq[t]=sq; __syncthreads();
  for (int st=128; st>0; st>>=1){ if (t<st){ rs[t]+=rs[t+st]; rq[t]+=rq[t+st]; } __syncthreads(); }
  if (t==0){ ps[s*2048 + c*8+ch]=rs[0]; pq[s*2048 + c*8+ch]=rq[0]; }
}
__global__ __launch_bounds__(256) void k_vstat2(const float* __restrict__ ps, const float* __restrict__ pq,
                                                const float* __restrict__ g, const float* __restrict__ be,
                                                float* __restrict__ aVall, float* __restrict__ bVall){
  int s = blockIdx.x, c = threadIdx.x;
  float sm=0.f, sq=0.f;
  #pragma unroll
  for (int ch=0; ch<8; ++ch){ sm += ps[s*2048 + c*8+ch]; sq += pq[s*2048 + c*8+ch]; }
  float mean = sm*(1.f/65536.f);
  float var  = sq*(1.f/65536.f) - mean*mean;
  float aa = g[c]*rsqrtf(var + 1e-5f);
  aVall[s*256+c]=aa; bVall[s*256+c]=be[c]-aa*mean;
}

// ---------- staging helpers for k_attn ----------
__device__ __forceinline__ void stageK(const u16* Kn, u16* kb, int kt, int wid, int l){
  #pragma unroll
  for (int c2=0; c2<2; ++c2){
    int off = wid*2048 + c2*1024 + l*16;            // byte offset in 8KB tile
    int row = off>>9, inb = off&511;
    int src = inb ^ ((row&7)<<4);                   // pre-swizzled source
    gload_lds16(Kn + (size_t)(kt*16+row)*256 + (src>>1), kb + wid*1024 + c2*512);
  }
}
// V tile 16KB: channel c holds its 32-k chunk at byte c*64; 16B slot swizzled by (c>>1)&3
__device__ __forceinline__ void stageV(const u16* Vn, u16* vb, int k0, int wid, int l){
  #pragma unroll
  for (int c4=0; c4<4; ++c4){
    int off = wid*4096 + c4*1024 + l*16;            // byte offset in 16KB tile
    int crow = off>>6, slot = (off>>4)&3;
    int kk = slot ^ ((crow>>1)&3);                  // pre-swizzled source chunk
    gload_lds16(Vn + (size_t)crow*512 + k0 + (kk<<3), vb + ((wid*4096 + c4*1024)>>1));
  }
}

// ---------- banded attention v4: counted-vmcnt deep pipeline, P in registers ----------
__global__ __launch_bounds__(256) void k_attn(
    const u16* __restrict__ Q1, const u16* __restrict__ K2, const u16* __restrict__ V2,
    const u16* __restrict__ Q2, const u16* __restrict__ K1, const u16* __restrict__ V1,
    const float* __restrict__ aVall, const float* __restrict__ bVall,
    u16* __restrict__ O1, u16* __restrict__ O2){
  __shared__ __align__(16) u16 SB[24576];            // 48KB: K 4x8KB, then V 3x16KB
  int t = threadIdx.x, wid = t>>6, l = t&63, lr = l&15, lg = l>>4;
  int id = blockIdx.x;
  int s = id >> 10;
  int r0 = id & 1023;
  int xcd = r0 & 7, s5 = r0 >> 3;
  int qb = s5 & 7, n = (xcd<<4) | (s5>>3);
  const u16* Q = s ? Q2 : Q1;
  const u16* K = s ? K1 : K2;
  const u16* V = s ? V1 : V2;
  const float* aV = aVall + (s ? 0 : 256);
  const float* bV = bVall + (s ? 0 : 256);
  u16* O = s ? O2 : O1;

  int q0 = qb*64, q0w = q0 + wid*16;
  int lo = q0 - 132; if (lo < 0) lo = 0;
  int hi = q0 + 195; if (hi > 511) hi = 511;
  int KTLO = (lo>>4) & ~1;                           // even
  int KTHI = (hi>>4) | 1;                            // odd
  int NT = KTHI - KTLO + 1;                          // even, 14..24
  int NK1 = NT - 1;
  int nksp = NT >> 1;                                // 7..12

  const u16* Kn = K + (size_t)n*131072;
  const u16* Vn = V + (size_t)n*131072;

  // Q frags first; drain so vmcnt literals below are exact
  bfrag qa[8];
  const u16* Qrow = Q + ((size_t)(n*512 + q0w + lr))*256 + lg*8;
  #pragma unroll
  for (int ks=0; ks<8; ++ks) qa[ks] = ldb(Qrow + ks*32);
  WAITV(0);

  // prologue: stage K tiles 0,1,2 (depth 3); 2 vmem instr per stage per wave
  stageK(Kn, SB + 0*4096, KTLO+0, wid, l);
  stageK(Kn, SB + 1*4096, KTLO+1, wid, l);
  stageK(Kn, SB + 2*4096, KTLO+2, wid, l);

  const ffrag fz = {0.f,0.f,0.f,0.f};
  ffrag acc[24];
  #pragma unroll
  for (int i=0;i<24;++i) acc[i] = fz;

  // phase 1: S^T tiles = mfma(K, Q); counted vmcnt keeps 2 tiles in flight
  #pragma unroll
  for (int j=0; j<24; ++j){
    if (j < NT){
      WAITV(4); RBAR();
      int jn = j+3; if (jn > NK1) jn = NK1;          // clamp keeps count invariant
      stageK(Kn, SB + ((j+3)&3)*4096, KTLO+jn, wid, l);
      const u16* kbuf = SB + (j&3)*4096;
      #pragma unroll
      for (int ks=0; ks<8; ++ks){
        int boff = (ks*64 + lg*16) ^ ((lr&7)<<4);
        bfrag kf = ldb(kbuf + lr*256 + (boff>>1));
        acc[j] = MFMA16(kf, qa[ks], acc[j]);
      }
    }
  }
  WAITV(0); RBAR();                                  // K phase done; SB free for V

  // V prologue (depth 2): 4 vmem instr per stage per wave
  stageV(Vn, SB + 0*8192, KTLO*16 + 0*32, wid, l);
  stageV(Vn, SB + 1*8192, KTLO*16 + 1*32, wid, l);

  // phase 2: in-register softmax (overlaps V stage latency)
  int q = q0w + lr;
  float m = -1e30f;
  #pragma unroll
  for (int j=0;j<24;++j){
    if (j < NT){
      int colb = (KTLO+j)*16 + lg*4;
      #pragma unroll
      for (int r=0;r<4;++r){
        int d = q - (colb + r);
        bool v = (d < 133) && (d > -133);
        m = v ? fmaxf(m, acc[j][r]) : m;
      }
    }
  }
  m = fmaxf(m, __shfl_xor(m, 16, 64));
  m = fmaxf(m, __shfl_xor(m, 32, 64));
  float sum = 0.f;
  #pragma unroll
  for (int j=0;j<24;++j){
    if (j < NT){
      int colb = (KTLO+j)*16 + lg*4;
      #pragma unroll
      for (int r=0;r<4;++r){
        int d = q - (colb + r);
        bool v = (d < 133) && (d > -133);
        float e = v ? __expf(acc[j][r] - m) : 0.f;
        acc[j][r] = e; sum += e;
      }
    }
  }
  sum += __shfl_xor(sum, 16, 64);
  sum += __shfl_xor(sum, 32, 64);
  float rinv = 1.f / sum;

  // pack P -> bf16 pairs in registers (lane holds P[q0w+lr][tile j, cols lg*4+r])
  unsigned pk0[24], pk1[24];
  #pragma unroll
  for (int j=0;j<24;++j){
    if (j < NT){
      pk0[j] = (unsigned)f2bf(acc[j][0]*rinv) | ((unsigned)f2bf(acc[j][1]*rinv) << 16);
      pk1[j] = (unsigned)f2bf(acc[j][2]*rinv) | ((unsigned)f2bf(acc[j][3]*rinv) << 16);
    } else { pk0[j] = 0u; pk1[j] = 0u; }
  }

  // phase 3: O = P*V ; PV A-frag rebuilt via shfl (no LDS for P)
  int s0l = lr + (lg&1)*32;                          // source lane for low 4 cols
  bool hi2 = (lg & 2) != 0;                          // tile-pair select
  int vswz = (lg ^ ((lr>>1)&3))<<3;                  // V read swizzle (u16 units)
  ffrag o[16];
  #pragma unroll
  for (int i=0;i<16;++i) o[i] = fz;

  #pragma unroll
  for (int ksp=0; ksp<12; ++ksp){
    if (ksp < nksp){
      WAITV(4); RBAR();
      int kn = ksp+2; if (kn > nksp-1) kn = nksp-1;
      stageV(Vn, SB + ((ksp+2)%3)*8192, KTLO*16 + kn*32, wid, l);

      unsigned a0 = (unsigned)__shfl((int)pk0[2*ksp],   s0l,    64);
      unsigned a1 = (unsigned)__shfl((int)pk1[2*ksp],   s0l,    64);
      unsigned a2 = (unsigned)__shfl((int)pk0[2*ksp],   s0l+16, 64);
      unsigned a3 = (unsigned)__shfl((int)pk1[2*ksp],   s0l+16, 64);
      unsigned b0 = (unsigned)__shfl((int)pk0[2*ksp+1], s0l,    64);
      unsigned b1 = (unsigned)__shfl((int)pk1[2*ksp+1], s0l,    64);
      unsigned b2 = (unsigned)__shfl((int)pk0[2*ksp+1], s0l+16, 64);
      unsigned b3 = (unsigned)__shfl((int)pk1[2*ksp+1], s0l+16, 64);
      unsigned pu[4];
      pu[0] = hi2 ? b0 : a0;  pu[1] = hi2 ? b1 : a1;
      pu[2] = hi2 ? b2 : a2;  pu[3] = hi2 ? b3 : a3;
      bfrag pa; __builtin_memcpy(&pa, pu, 16);

      const u16* vbuf = SB + (ksp%3)*8192;
      #pragma unroll
      for (int ct=0; ct<16; ++ct){
        bfrag vf = ldb(vbuf + (ct*16 + lr)*32 + vswz);
        o[ct] = MFMA16(pa, vf, o[ct]);
      }
    }
  }

  #pragma unroll
  for (int ct=0; ct<16; ++ct){
    int c = ct*16 + lr;
    float av = aV[c], bv = bV[c];
    #pragma unroll
    for (int r=0;r<4;++r)
      O[((size_t)(n*512 + q0w + lg*4 + r))*256 + c] = f2bf(av*o[ct][r] + bv);
  }
}

// ---------- u BN stats stage 2 (reduces conv1's fused partials) ----------
__global__ __launch_bounds__(256) void k_ustat2(const float* __restrict__ psum, const float* __restrict__ psq,
                                                const float* __restrict__ g, const float* __restrict__ be,
                                                float* __restrict__ aWall, float* __restrict__ bWall){
  int c = blockIdx.x, s = blockIdx.y, t = threadIdx.x;
  const float* ps = psum + (((size_t)s*256 + c)<<10);
  const float* pq = psq  + (((size_t)s*256 + c)<<10);
  float sm = ps[t] + ps[t+256] + ps[t+512] + ps[t+768];
  float sq = pq[t] + pq[t+256] + pq[t+512] + pq[t+768];
  __shared__ float rs[256], rq[256];
  rs[t]=sm; rq[t]=sq; __syncthreads();
  for (int st=128; st>0; st>>=1){ if (t<st){ rs[t]+=rs[t+st]; rq[t]+=rq[t+st]; } __syncthreads(); }
  if (t==0){
    float mean = rs[0]*(1.f/65536.f);
    float var  = rq[0]*(1.f/65536.f) - mean*mean;
    float aa = g[c]*rsqrtf(var + 1e-5f);
    aWall[s*256+c]=aa; bWall[s*256+c]=be[c]-aa*mean;
  }
}

// ---------- final: z = aW*u + bW + xr (bf16 residual), transpose back ----------
__global__ __launch_bounds__(256) void k_final(const u16* __restrict__ u1, const u16* __restrict__ u2,
                                               const u16* __restrict__ xr1, const u16* __restrict__ xr2,
                                               const float* __restrict__ aWall, const float* __restrict__ bWall,
                                               float* __restrict__ z){
  int s = blockIdx.z;
  const u16* u  = s ? u2 : u1;
  const u16* xr = s ? xr2 : xr1;
  const float* aW = aWall + s*256;
  const float* bW = bWall + s*256;
  float* zb = z + (size_t)s*16777216;
  __shared__ u16 Tu[64][66], Tx[64][66];
  int t = threadIdx.x;
  int p0 = blockIdx.x*64, c0 = blockIdx.y*64;
  int b = p0>>15, q0 = p0&32767;
  #pragma unroll
  for (int it=0; it<4; ++it){
    int pi = it*16 + (t>>4);
    int cj = (t&15)*4;
    u16x4 vu; __builtin_memcpy(&vu, u  + (size_t)(p0+pi)*256 + c0 + cj, 8);
    u16x4 vx; __builtin_memcpy(&vx, xr + (size_t)(p0+pi)*256 + c0 + cj, 8);
    *reinterpret_cast<u16x4*>(&Tu[pi][cj]) = vu;
    *reinterpret_cast<u16x4*>(&Tx[pi][cj]) = vx;
  }
  __syncthreads();
  #pragma unroll
  for (int it=0; it<16; ++it){
    int cc = it*4 + (t>>6);
    int qi = t&63;
    size_t addr = ((size_t)(b*256 + c0 + cc))*32768 + q0 + qi;
    zb[addr] = aW[c0+cc]*bf2f(Tu[qi][cc]) + bW[c0+cc] + bf2f(Tx[qi][cc]);
  }
}

extern "C" void kernel_launch(void* const* d_in, const int* in_sizes, int n_in,
                              void* d_out, int out_size, void* d_ws, size_t ws_size,
                              hipStream_t stream) {
  const float* x1  = (const float*)d_in[0];
  const float* x2  = (const float*)d_in[1];
  const float* Qw  = (const float*)d_in[2];
  const float* Qb  = (const float*)d_in[3];
  const float* Kw  = (const float*)d_in[4];
  const float* Kb  = (const float*)d_in[5];
  const float* Vw  = (const float*)d_in[6];
  const float* Vb  = (const float*)d_in[7];
  const float* Vg  = (const float*)d_in[8];
  const float* Vbe = (const float*)d_in[9];
  const float* Ww  = (const float*)d_in[10];
  const float* Wb  = (const float*)d_in[11];
  const float* Wg  = (const float*)d_in[12];
  const float* Wbe = (const float*)d_in[13];

  char* ws = (char*)d_ws;
  const size_t S = 33554432;                  // one (65536 x 256) bf16 slot = 32 MB
  u16* xr1 = (u16*)(ws + 0*S);                // stays live through k_final
  u16* xr2 = (u16*)(ws + 1*S);
  u16* Q1  = (u16*)(ws + 2*S);                // later reused as u1
  u16* K1  = (u16*)(ws + 3*S);                // later reused as u2
  u16* Q2  = (u16*)(ws + 4*S);
  u16* K2  = (u16*)(ws + 5*S);
  u16* wb  = (u16*)(ws + 6*S);                // 4 x 65536 bf16 = 512KB
  float* vec = (float*)(ws + 6*S + 524288);
  float* aVall = vec;                         // [2][256]
  float* bVall = vec + 512;
  float* aWall = vec + 1024;
  float* bWall = vec + 1536;
  float* vps   = vec + 2048;                  // [2][2048]
  float* vpq   = vps + 4096;

  char* douts = (char*)d_out;                 // d_out = 128MB; scratch dead before z writes
  u16* Vt1 = (u16*)douts;                     // [0,32MB)   read by vstat1/attn
  u16* Vt2 = (u16*)(douts + S);               // [32,64MB)
  u16* O1  = (u16*)(douts + 2*S);             // [64,96MB)  written by attn, read by conv1
  u16* O2  = (u16*)(douts + 3*S);             // [96,128MB)
  float* upsum = (float*)douts;               // [0,2MB)  reuses dead Vt1 slot after attn
  float* upsq  = upsum + 524288;              // [2,4MB)
  u16* u1 = Q1;  u16* u2 = K1;
  float* z = (float*)d_out;

  dim3 gt(1024, 4, 2);
  dim3 gv(256, 8, 2);
  dim3 gu2(256, 2);

  k_wcvt<<<256, 256, 0, stream>>>(Qw, Kw, Vw, Ww, wb);
  k_xpose<<<gt, 256, 0, stream>>>(x1, x2, xr1, xr2);
  k_qkv<<<6144, 256, 0, stream>>>(xr1, xr2, wb, Qb, Kb, Vb, Q1, K1, Vt1, Q2, K2, Vt2);
  k_vstat1<<<gv, 256, 0, stream>>>(Vt1, Vt2, vps, vpq);
  k_vstat2<<<2, 256, 0, stream>>>(vps, vpq, Vg, Vbe, aVall, bVall);
  k_attn<<<2048, 256, 0, stream>>>(Q1, K2, Vt2, Q2, K1, Vt1, aVall, bVall, O1, O2);
  k_conv1<<<2048, 256, 0, stream>>>(O1, O2, wb + 196608, Wb, u1, u2, upsum, upsq);
  k_ustat2<<<gu2, 256, 0, stream>>>(upsum, upsq, Wg, Wbe, aWall, bWall);
  k_final<<<gt, 256, 0, stream>>>(u1, u2, xr1, xr2, aWall, bWall, z);
}